// Round 8
// baseline (1277.642 us; speedup 1.0000x reference)
//
#include <hip/hip_runtime.h>
#include <hip/hip_bf16.h>
#include <math.h>

// Problem dims
#define BB 8
#define TT 16
#define HH 112
#define WW 112
#define CC 3
#define FF 16
#define HP 56
#define WP 56
#define HO 54
#define WO 54
#define NC 6

#define NPIX (BB*HO*WO)               // 23328
#define SPIX (HO*WO)                  // 2916
#define NPT  (BB*TT*SPIX)             // 373248  (b,t,pixel)
#define POOLED_BF16  (128*56*56*16)   // 6,422,528 bf16

// xpad: per-frame bf16 rows with halo + pad: 118 rows x 360 elems
#define XROW 360
#define XFRM (118*XROW)               // 42,480
#define XPAD_ELEMS (128*XFRM)         // 5,437,440 per parity copy

typedef __attribute__((ext_vector_type(8))) short s8v;   // 8 bf16 (4 VGPRs)
typedef __attribute__((ext_vector_type(4))) float f4v;   // MFMA acc

__device__ __forceinline__ float hsig(float x) {
    return fminf(fmaxf(0.2f*x + 0.5f, 0.0f), 1.0f);
}
__device__ __forceinline__ unsigned pk2(float lo, float hi) {
    union { __hip_bfloat16 h; unsigned short u; } a, b;
    a.h = __float2bfloat16(lo); b.h = __float2bfloat16(hi);
    return ((unsigned)b.u << 16) | (unsigned)a.u;
}
__device__ __forceinline__ float bf2f(unsigned short u) {
    union { unsigned v; float f; } x; x.v = ((unsigned)u) << 16; return x.f;
}
__device__ __forceinline__ unsigned short f2bfu(float f) {
    union { __hip_bfloat16 h; unsigned short u; } v;
    v.h = __float2bfloat16(f); return v.u;
}

// Kernel 0a: prepack a [3,3,16,64] weight tensor into MFMA B-fragment order
// (K=144 pad 160): out[nt][ks][lane][j]. Used for BOTH wk and wr.
__global__ __launch_bounds__(256) void w_prepack_kernel(
    const float* __restrict__ w, __hip_bfloat16* __restrict__ wb)
{
    int i = blockIdx.x * 256 + threadIdx.x;        // 40*256 = 10240 exact
    int j    = i & 7;
    int lane = (i >> 3) & 63;
    int ks   = (i >> 9) % 5;
    int nt   = (i >> 9) / 5;
    int k = ks*32 + ((lane >> 4) & 3)*8 + j;
    int n = nt*16 + (lane & 15);
    float v = 0.f;
    if (k < 144) {
        int tap = k >> 4, ci = k & 15;
        v = w[tap*1024 + ci*64 + n];
    }
    wb[i] = __float2bfloat16(v);
}

// Kernel 0b: prepack conv weights [7,7,3,16] (K = 7 rows x 24, pad 192).
__global__ __launch_bounds__(256) void cw_prepack_kernel(
    const float* __restrict__ cw, __hip_bfloat16* __restrict__ cwb)
{
    int i = blockIdx.x * 256 + threadIdx.x;        // 12*256 = 3072 exact
    int j    = i & 7;
    int lane = (i >> 3) & 63;
    int ks   = i >> 9;                             // 0..5
    int k = ks*32 + ((lane >> 4) & 3)*8 + j;
    int n = lane & 15;
    float v = 0.f;
    if (k < 168) {
        int row = k / 24, idx = k % 24;
        if (idx < 21) {
            int kx = idx / 3, ci = idx % 3;
            v = cw[((row*7 + kx)*3 + ci)*16 + n];
        }
    }
    cwb[i] = __float2bfloat16(v);
}

// Kernel 0c: build bf16 padded x rows, TWO parity-shifted copies.
__global__ __launch_bounds__(256) void xpad_kernel(
    const float* __restrict__ x,
    __hip_bfloat16* __restrict__ xp0,
    __hip_bfloat16* __restrict__ xp1)
{
    int idx = blockIdx.x * 256 + threadIdx.x;      // 5310*256 = 1,359,360 exact
    int e4 = idx % 90;
    int rr = (idx / 90) % 118;
    int fr = idx / (90*118);
    int e0 = e4 * 4;
    int ir = rr - 3;
    const float* xf = x + (size_t)fr * (112*336);
    bool rowok = (ir >= 0) & (ir < 112);

    float v[5];
    #pragma unroll
    for (int i = 0; i < 5; ++i) {
        int s = e0 - 1 + i;
        bool ok = rowok & (s >= 9) & (s < 345);
        v[i] = ok ? xf[ir*336 + (s - 9)] : 0.f;
    }
    size_t o = ((size_t)fr*118 + rr) * XROW + e0;
    uint2 a0, a1;
    a0.x = pk2(v[1], v[2]); a0.y = pk2(v[3], v[4]);
    a1.x = pk2(v[0], v[1]); a1.y = pk2(v[2], v[3]);
    *(uint2*)&xp0[o] = a0;
    *(uint2*)&xp1[o] = a1;
}

// Kernel 1: conv 7x7 + bias + relu + maxpool via MFMA.
// R20: LDS-staged input rows (verified win: 47.6 -> ~15 us).
__global__ __launch_bounds__(256, 6) void conv_mfma_kernel(
    const __hip_bfloat16* __restrict__ xp0,
    const __hip_bfloat16* __restrict__ xp1,
    const __hip_bfloat16* __restrict__ cwb,  // [6][64][8]
    const float* __restrict__ cb,            // [16]
    __hip_bfloat16* __restrict__ pooled)     // [128,56,56,16] bf16
{
    int wv = threadIdx.x >> 6;
    int lane = threadIdx.x & 63;
    int quad = lane >> 4;
    int fr = blockIdx.y;
    int p0b = blockIdx.x * 64;               // block's pooled px base
    int p0 = p0b + wv * 16;                  // wave's pooled px base

    // ---- stage: lx[par][10 rows][368 elems] (row padded 360->368) ----
    __shared__ short lx[2][10][368];         // 14,720 B
    int pr0 = p0b / 56;
    int ohb = 2 * pr0;                       // first staged input row
    {
        const __hip_bfloat16* s0 = xp0 + (size_t)fr*XFRM + (size_t)ohb*XROW;
        const __hip_bfloat16* s1 = xp1 + (size_t)fr*XFRM + (size_t)ohb*XROW;
        for (int u = threadIdx.x; u < 900; u += 256) {
            int par = u / 450;
            int rem = u - par*450;
            int rr  = rem / 45;
            int c   = rem - rr*45;           // 16B unit within row
            const __hip_bfloat16* s = (par ? s1 : s0) + rr*XROW + c*8;
            *(uint4*)&lx[par][rr][c*8] = *(const uint4*)s;
        }
    }
    __syncthreads();

    const s8v* wbp = (const s8v*)cwb;
    s8v bfrag[6];
    #pragma unroll
    for (int ks = 0; ks < 6; ++ks) bfrag[ks] = wbp[ks*64 + lane];

    const unsigned* lx32 = (const unsigned*)&lx[0][0][0];

    f4v acc[4];
    #pragma unroll
    for (int j = 0; j < 4; ++j) {
        int mm = lane & 15;
        int pp = p0 + j*4 + (mm >> 2);
        int pos = mm & 3;
        int pr = pp / 56, pc = pp - pr*56;
        int lr = 2*pr - ohb + (pos >> 1);    // 0..3
        int ow = 2*pc + (pos & 1);
        // dword base within lx: parity plane + row + elem offset (always even)
        const unsigned* xr = lx32 + ((ow & 1)*10 + lr)*184 + ((ow*3 + (ow & 1)) >> 1);

        f4v a4 = {0.f,0.f,0.f,0.f};
        #pragma unroll
        for (int ks = 0; ks < 6; ++ks) {
            int blk = ks*4 + quad;
            union { s8v v; unsigned u[4]; } av;
            av.v = (s8v){0,0,0,0,0,0,0,0};
            if (blk < 21) {
                int row = blk / 3;
                int off2 = (blk % 3) * 4;    // dwords
                const unsigned* p = xr + row*184 + off2;
                av.u[0] = p[0]; av.u[1] = p[1]; av.u[2] = p[2]; av.u[3] = p[3];
            }
            a4 = __builtin_amdgcn_mfma_f32_16x16x32_bf16(av.v, bfrag[ks], a4, 0,0,0);
        }
        acc[j] = a4;
    }

    // Epilogue: lane quad owns pooled px p0+j*4+quad, ch nlo; regs = 4 pos.
    int nlo = lane & 15;
    float bias_n = cb[nlo];
    #pragma unroll
    for (int j = 0; j < 4; ++j) {
        float* ap = (float*)&acc[j];
        float mx = fmaxf(fmaxf(ap[0], ap[1]), fmaxf(ap[2], ap[3]));
        float vv = fmaxf(mx + bias_n, 0.f);
        ((unsigned short*)pooled)[((size_t)fr*3136 + p0 + j*4 + quad)*16 + nlo] = f2bfu(vv);
    }
}

// Kernel 2a: zx via MFMA (R14, verified). One wave = 16 pt x 64 gates.
__global__ __launch_bounds__(256, 4) void zx_mfma_kernel(
    const __hip_bfloat16* __restrict__ pooled,  // [128][56][56][16] bf16
    const __hip_bfloat16* __restrict__ wkb,     // [4][5][64][8] bf16
    __hip_bfloat16* __restrict__ zx)            // [64][373248] bf16
{
    int wid  = (blockIdx.x << 2) + (threadIdx.x >> 6);  // 0..23327
    int lane = threadIdx.x & 63;
    int quad = lane >> 4;
    int pt0  = wid << 4;
    int m    = pt0 + (lane & 15);

    int b  = m / (TT*SPIX);
    int rt = m % (TT*SPIX);
    int tt = rt / SPIX;
    int r  = rt % SPIX;
    int oh = r / WO, ow = r % WO;
    const __hip_bfloat16* pf = pooled + (size_t)(b*TT + tt) * (HP*WP*16);

    f4v acc0 = {0.f,0.f,0.f,0.f}, acc1 = acc0, acc2 = acc0, acc3 = acc0;
    const s8v* wb = (const s8v*)wkb;

    #pragma unroll
    for (int ks = 0; ks < 5; ++ks) {
        int blk = ks*4 + quad;
        s8v a;
        if (blk < 18) {
            int tap = blk >> 1, half = blk & 1;
            int ky = tap / 3, kx = tap - ky*3;
            a = *(const s8v*)(pf + ((size_t)(oh+ky)*WP + (ow+kx))*16 + half*8);
        } else {
            a = (s8v){0,0,0,0,0,0,0,0};
        }
        acc0 = __builtin_amdgcn_mfma_f32_16x16x32_bf16(a, wb[(0*5+ks)*64 + lane], acc0, 0,0,0);
        acc1 = __builtin_amdgcn_mfma_f32_16x16x32_bf16(a, wb[(1*5+ks)*64 + lane], acc1, 0,0,0);
        acc2 = __builtin_amdgcn_mfma_f32_16x16x32_bf16(a, wb[(2*5+ks)*64 + lane], acc2, 0,0,0);
        acc3 = __builtin_amdgcn_mfma_f32_16x16x32_bf16(a, wb[(3*5+ks)*64 + lane], acc3, 0,0,0);
    }

    int nlo = lane & 15;
    size_t prow = (size_t)pt0 + quad*4;
    f4v accs[4] = {acc0, acc1, acc2, acc3};
    #pragma unroll
    for (int nt = 0; nt < 4; ++nt) {
        int n = nt*16 + nlo;
        uint2 u;
        u.x = pk2(accs[nt].x, accs[nt].y);
        u.y = pk2(accs[nt].z, accs[nt].w);
        *(uint2*)&zx[(size_t)n * NPT + prow] = u;
    }
}

// Kernel 2b (R25): PERSISTENT scan, neighbor-flag sync (no grid.sync).
// Model from R22/R23 post-mortems: step time = dispatch overhead (~10us) +
// per-wave serial tile latency (~2.5us/tile). Fixes: ONE dispatch (no 16x
// overhead), 1 tile/wave/step (no serialization), neighbor flags instead of
// grid.sync (65us/sync measured, R22).
// Block = (b, 3-row group): 18x8 = 144 blocks (co-resident via cooperative
// launch), 704 thr = 11 waves = 11 tiles = 3 rows + alignment pad.
// Per step: spin on 2 neighbor flags (agent-scope acquire; acquire emits the
// vL1 invalidate so halo reads are fresh) -> stage 2 halo rows (3.4KB) into
// LDS -> compute from LDS h (5 rows, parity double-buffer, ring cols; exact
// scan2-stepB indexing, verified R6 absmax=0) -> write h to LDS-next + global
// -> threadfence + release-store flag. c lives in REGISTERS all 16 steps
// (cpl buffer + memset + 48MB traffic deleted). h0 = LDS zeros; no h memset.
// Deadlock-free: flags monotone, deps are +-1 neighbor, all blocks resident.
__global__ __launch_bounds__(704, 2) void lstm_scan_flags(
    const __hip_bfloat16* __restrict__ zx,   // [64][373248]
    __hip_bfloat16* __restrict__ hA,         // h parity 0 (h16 lands here)
    __hip_bfloat16* __restrict__ hB,         // h parity 1
    const __hip_bfloat16* __restrict__ wrb,  // [4][5][64][8] bf16
    const float* __restrict__ bias,          // [64]
    int* __restrict__ flags)                 // [8][18], zeroed
{
    int g = blockIdx.x;                      // 0..17 row group, y0 = 3g
    int b = blockIdx.y;                      // 0..7
    int y0 = 3*g;
    int tid  = threadIdx.x;
    int wv   = tid >> 6;                     // 0..10
    int lane = tid & 63;
    int quad = lane >> 4;
    int ml   = lane & 15;
    int ch   = ml;

    // h_t rows y0-1..y0+3, ring cols (0 and 55 stay zero), parity-dbuf.
    __shared__ __align__(16) short hbuf[2][5][56][16];   // 17,920 B
    {
        uint4* hz = (uint4*)hbuf;            // 1120 uint4
        for (int u = tid; u < 1120; u += 704) hz[u] = (uint4){0,0,0,0};
    }

    const s8v* wbv = (const s8v*)wrb;
    s8v bfr[20];
    #pragma unroll
    for (int i = 0; i < 20; ++i) bfr[i] = wbv[i*64 + lane];

    float b_i = bias[ch], b_f = bias[16+ch], b_g = bias[32+ch], b_o = bias[48+ch];

    // Fixed per-thread geometry (identical to scan2 step B, verified).
    int rlo = y0*54, rhi = rlo + 162;
    int rb  = rlo - (rlo & 3);               // aligned region start
    int pt0 = wv << 4;
    int rm  = rb + pt0 + ml;                 // lane pixel for A-frags
    int yB  = rm / 54, xB = rm - yB*54;
    int lrB = yB - y0;

    int r0 = rb + pt0 + quad*4;              // epilogue base px (mult of 4)

    const unsigned short* zxp = (const unsigned short*)zx;
    int* myflag = flags + b*18 + g;
    int* flagL  = (g > 0)  ? (flags + b*18 + g - 1) : (int*)0;
    int* flagR  = (g < 17) ? (flags + b*18 + g + 1) : (int*)0;

    float4 creg = {0.f, 0.f, 0.f, 0.f};      // c state, register-resident

    __syncthreads();                          // LDS zeros visible

    #pragma unroll 1
    for (int t = 0; t < TT; ++t) {
        short (*bufR)[56][16] = hbuf[t & 1];
        short (*bufW)[56][16] = hbuf[(t + 1) & 1];

        if (t > 0) {
            // Wait for neighbors' h_t (all threads: every wave acquires).
            if (flagL) while (__hip_atomic_load(flagL, __ATOMIC_ACQUIRE,
                              __HIP_MEMORY_SCOPE_AGENT) < t)
                __builtin_amdgcn_s_sleep(2);
            if (flagR) while (__hip_atomic_load(flagR, __ATOMIC_ACQUIRE,
                              __HIP_MEMORY_SCOPE_AGENT) < t)
                __builtin_amdgcn_s_sleep(2);
            // Stage halo rows y0-1 -> bufR[0], y0+3 -> bufR[4].
            const unsigned short* hGin =
                (const unsigned short*)((t & 1) ? hB : hA);
            for (int u = tid; u < 216; u += 704) {
                int rsel = u / 108;          // 0: y0-1, 1: y0+3
                int rem  = u - rsel*108;
                int px = rem >> 1, half = rem & 1;
                int ry = rsel ? (y0 + 3) : (y0 - 1);
                uint4 v = (uint4){0,0,0,0};
                if ((ry >= 0) && (ry < HO))
                    v = *(const uint4*)&hGin[((size_t)b*SPIX + ry*54 + px)*16 + half*8];
                *(uint4*)&bufW[0][0][0];     // (no-op; keep compiler honest)
                *(uint4*)&bufR[rsel ? 4 : 0][px + 1][half*8] = v;
            }
        }
        __syncthreads();                     // halo staged; bufR complete

        // A-fragments from LDS (scan2 step-B indexing, row clamp for pads).
        s8v afr[5];
        #pragma unroll
        for (int ks = 0; ks < 5; ++ks) {
            int blk = ks*4 + quad;
            s8v a = (s8v){0,0,0,0,0,0,0,0};
            if (blk < 18) {
                int tap = blk >> 1, half = blk & 1;
                int ky = tap / 3, kx = tap - ky*3;
                int row = lrB + ky;
                row = row < 0 ? 0 : (row > 4 ? 4 : row);
                a = *(const s8v*)&bufR[row][xB + kx][half*8];
            }
            afr[ks] = a;
        }

        // zx gate inputs for this step.
        size_t zb = (size_t)b*(TT*SPIX) + (size_t)t*SPIX;
        ushort4 zi, zf, zg_, zo;
        if ((r0 >= rlo) && (r0 + 3 < rhi)) {
            zi  = *(const ushort4*)&zxp[(size_t)( 0+ch)*NPT + zb + r0];
            zf  = *(const ushort4*)&zxp[(size_t)(16+ch)*NPT + zb + r0];
            zg_ = *(const ushort4*)&zxp[(size_t)(32+ch)*NPT + zb + r0];
            zo  = *(const ushort4*)&zxp[(size_t)(48+ch)*NPT + zb + r0];
        } else {
            unsigned short* zv[4] = {(unsigned short*)&zi, (unsigned short*)&zf,
                                     (unsigned short*)&zg_, (unsigned short*)&zo};
            #pragma unroll
            for (int e = 0; e < 4; ++e) {
                int re = r0 + e;
                bool ok = (re >= rlo) & (re < rhi);
                #pragma unroll
                for (int gg = 0; gg < 4; ++gg)
                    zv[gg][e] = ok ? zxp[(size_t)(gg*16+ch)*NPT + zb + re] : 0;
            }
        }

        f4v acc0 = {0.f,0.f,0.f,0.f}, acc1 = acc0, acc2 = acc0, acc3 = acc0;
        #pragma unroll
        for (int ks = 0; ks < 5; ++ks) {
            acc0 = __builtin_amdgcn_mfma_f32_16x16x32_bf16(afr[ks], bfr[0*5+ks], acc0, 0,0,0);
            acc1 = __builtin_amdgcn_mfma_f32_16x16x32_bf16(afr[ks], bfr[1*5+ks], acc1, 0,0,0);
            acc2 = __builtin_amdgcn_mfma_f32_16x16x32_bf16(afr[ks], bfr[2*5+ks], acc2, 0,0,0);
            acc3 = __builtin_amdgcn_mfma_f32_16x16x32_bf16(afr[ks], bfr[3*5+ks], acc3, 0,0,0);
        }

        // Epilogue: lane owns (px r0..r0+3, ch); c in registers.
        unsigned short* hGnext = (unsigned short*)(((t + 1) & 1) ? hB : hA);
        const unsigned short* zip = (const unsigned short*)&zi;
        const unsigned short* zfp = (const unsigned short*)&zf;
        const unsigned short* zgp = (const unsigned short*)&zg_;
        const unsigned short* zop = (const unsigned short*)&zo;
        float* a0 = (float*)&acc0; float* a1 = (float*)&acc1;
        float* a2 = (float*)&acc2; float* a3 = (float*)&acc3;
        float* co = &creg.x;
        #pragma unroll
        for (int reg = 0; reg < 4; ++reg) {
            float iv = hsig (a0[reg] + bf2f(zip[reg]) + b_i);
            float fv = hsig (a1[reg] + bf2f(zfp[reg]) + b_f);
            float gv = tanhf(a2[reg] + bf2f(zgp[reg]) + b_g);
            float ov = hsig (a3[reg] + bf2f(zop[reg]) + b_o);
            float cc = fv * co[reg] + iv * gv;
            float hv = ov * tanhf(cc);
            co[reg] = cc;
            int rr = r0 + reg;
            if ((rr >= rlo) && (rr < rhi)) {
                int yy = rr / 54, xx = rr - yy*54;
                unsigned short hu = f2bfu(hv);
                bufW[yy - y0 + 1][xx + 1][ch] = (short)hu;     // own rows 1..3
                hGnext[((size_t)b*SPIX + rr)*16 + ch] = hu;    // for neighbors+head
            }
        }

        __threadfence();                     // drain global h writes (release)
        __syncthreads();                     // all waves done before publish
        if (tid == 0)
            __hip_atomic_store(myflag, t + 1, __ATOMIC_RELEASE,
                               __HIP_MEMORY_SCOPE_AGENT);
    }
}

// Kernel 3: spatial mean (bf16 h) -> dense(16->6) -> softmax. One block per b.
// R18: short8 loads, 1024 threads, parity-preserving LDS tree (verified win).
__global__ __launch_bounds__(1024) void head_kernel(
    const __hip_bfloat16* __restrict__ h,   // [8,54,54,16] bf16
    const float* __restrict__ dw,   // [16,6]
    const float* __restrict__ db,   // [6]
    float* __restrict__ out)        // [8,6]
{
    int b = blockIdx.x;
    int tid = threadIdx.x;
    const s8v* hb = (const s8v*)(h + (size_t)b * SPIX * 16);  // 5832 s8v per b

    float acc[8] = {0.f,0.f,0.f,0.f,0.f,0.f,0.f,0.f};
    for (int j = tid; j < SPIX*2; j += 1024) {
        s8v v = hb[j];
        #pragma unroll
        for (int k = 0; k < 8; ++k) acc[k] += bf2f((unsigned short)v[k]);
    }

    __shared__ float red[1024][8];           // 32 KB
    #pragma unroll
    for (int k = 0; k < 8; ++k) red[tid][k] = acc[k];
    __syncthreads();
    for (int st = 512; st >= 2; st >>= 1) {
        if (tid < st) {
            #pragma unroll
            for (int k = 0; k < 8; ++k) red[tid][k] += red[tid + st][k];
        }
        __syncthreads();
    }

    __shared__ float logits[8];
    if (tid < NC) {
        float l = db[tid];
        #pragma unroll
        for (int k = 0; k < 8; ++k) {
            l += (red[0][k] * (1.0f/2916.0f)) * dw[k*NC + tid];
            l += (red[1][k] * (1.0f/2916.0f)) * dw[(8+k)*NC + tid];
        }
        logits[tid] = l;
    }
    __syncthreads();
    if (tid < NC) {
        float m = -1e30f;
        for (int k = 0; k < NC; ++k) m = fmaxf(m, logits[k]);
        float e = expf(logits[tid] - m);
        float d = 0.0f;
        for (int k = 0; k < NC; ++k) d += expf(logits[k] - m);
        out[b*NC + tid] = e / d;
    }
}

extern "C" void kernel_launch(void* const* d_in, const int* in_sizes, int n_in,
                              void* d_out, int out_size, void* d_ws, size_t ws_size,
                              hipStream_t stream) {
    const float* x      = (const float*)d_in[0];
    const float* conv_w = (const float*)d_in[1];
    const float* conv_b = (const float*)d_in[2];
    const float* wk     = (const float*)d_in[3];
    const float* wr     = (const float*)d_in[4];
    const float* bias   = (const float*)d_in[5];
    const float* dw     = (const float*)d_in[6];
    const float* db     = (const float*)d_in[7];
    float* out = (float*)d_out;

    char* base = (char*)d_ws;
    __hip_bfloat16* pooled = (__hip_bfloat16*)base;                 // 12.85 MB
    __hip_bfloat16* hA  = pooled + POOLED_BF16;                     // 746 KB
    __hip_bfloat16* hB  = hA + NPIX*16;
    __hip_bfloat16* wkb = hB + NPIX*16;                             // 20 KB
    __hip_bfloat16* wrb = wkb + 10240;                              // 20 KB
    __hip_bfloat16* cwb = wrb + 10240;                              // 6 KB
    int* flags = (int*)(cwb + 3072);                                // 576 B (pad 1KB)
    __hip_bfloat16* zx  = (__hip_bfloat16*)((char*)flags + 1024);   // 47.8 MB
    // xpad parity copies ALIAS zx (consumed before zx is written).
    __hip_bfloat16* xp0 = zx;
    __hip_bfloat16* xp1 = zx + XPAD_ELEMS;

    // flags = 0 (h0 comes from LDS zeros; c0 in registers; no h/c memsets)
    hipMemsetAsync(flags, 0, 18*8*sizeof(int), stream);

    w_prepack_kernel<<<dim3(40), dim3(256), 0, stream>>>(wk, wkb);
    w_prepack_kernel<<<dim3(40), dim3(256), 0, stream>>>(wr, wrb);
    cw_prepack_kernel<<<dim3(12), dim3(256), 0, stream>>>(conv_w, cwb);
    xpad_kernel<<<dim3(5310), dim3(256), 0, stream>>>(x, xp0, xp1);
    conv_mfma_kernel<<<dim3(49, 128), dim3(256), 0, stream>>>(xp0, xp1, cwb, conv_b, pooled);
    zx_mfma_kernel<<<dim3(5832), dim3(256), 0, stream>>>(pooled, wkb, zx);

    // Whole 16-step scan: ONE cooperative dispatch, neighbor-flag sync.
    {
        const __hip_bfloat16* kzx = zx;
        __hip_bfloat16* khA = hA;
        __hip_bfloat16* khB = hB;
        const __hip_bfloat16* kwrb = wrb;
        const float* kbias = bias;
        int* kflags = flags;
        void* kargs[] = { (void*)&kzx, (void*)&khA, (void*)&khB,
                          (void*)&kwrb, (void*)&kbias, (void*)&kflags };
        hipLaunchCooperativeKernel((const void*)lstm_scan_flags,
                                   dim3(18, 8), dim3(704), kargs, 0, stream);
    }
    // h16 = hG[(15+1)&1] = hG[0] = hA
    head_kernel<<<dim3(8), dim3(1024), 0, stream>>>(hA, dw, db, out);
}

// Round 9
// 312.799 us; speedup vs baseline: 4.0845x; 4.0845x over previous
//
#include <hip/hip_runtime.h>
#include <hip/hip_bf16.h>
#include <math.h>

// Problem dims
#define BB 8
#define TT 16
#define HH 112
#define WW 112
#define CC 3
#define FF 16
#define HP 56
#define WP 56
#define HO 54
#define WO 54
#define NC 6

#define NPIX (BB*HO*WO)               // 23328
#define SPIX (HO*WO)                  // 2916
#define NPT  (BB*TT*SPIX)             // 373248  (b,t,pixel)
#define POOLED_BF16  (128*56*56*16)   // 6,422,528 bf16

// xpad: per-frame bf16 rows with halo + pad: 118 rows x 360 elems
#define XROW 360
#define XFRM (118*XROW)               // 42,480
#define XPAD_ELEMS (128*XFRM)         // 5,437,440 per parity copy

typedef __attribute__((ext_vector_type(8))) short s8v;   // 8 bf16 (4 VGPRs)
typedef __attribute__((ext_vector_type(4))) float f4v;   // MFMA acc

__device__ __forceinline__ float hsig(float x) {
    return fminf(fmaxf(0.2f*x + 0.5f, 0.0f), 1.0f);
}
__device__ __forceinline__ unsigned pk2(float lo, float hi) {
    union { __hip_bfloat16 h; unsigned short u; } a, b;
    a.h = __float2bfloat16(lo); b.h = __float2bfloat16(hi);
    return ((unsigned)b.u << 16) | (unsigned)a.u;
}
__device__ __forceinline__ float bf2f(unsigned short u) {
    union { unsigned v; float f; } x; x.v = ((unsigned)u) << 16; return x.f;
}
__device__ __forceinline__ unsigned short f2bfu(float f) {
    union { __hip_bfloat16 h; unsigned short u; } v;
    v.h = __float2bfloat16(f); return v.u;
}

// ---------- prep job bodies (verbatim logic, virtual block id) ----------
__device__ __forceinline__ void w_prepack_body(int vb, const float* __restrict__ w,
                                               __hip_bfloat16* __restrict__ wb)
{
    int i = vb * 256 + threadIdx.x;                // 40*256 = 10240 exact
    int j    = i & 7;
    int lane = (i >> 3) & 63;
    int ks   = (i >> 9) % 5;
    int nt   = (i >> 9) / 5;
    int k = ks*32 + ((lane >> 4) & 3)*8 + j;
    int n = nt*16 + (lane & 15);
    float v = 0.f;
    if (k < 144) {
        int tap = k >> 4, ci = k & 15;
        v = w[tap*1024 + ci*64 + n];
    }
    wb[i] = __float2bfloat16(v);
}

__device__ __forceinline__ void cw_prepack_body(int vb, const float* __restrict__ cw,
                                                __hip_bfloat16* __restrict__ cwb)
{
    int i = vb * 256 + threadIdx.x;                // 12*256 = 3072 exact
    int j    = i & 7;
    int lane = (i >> 3) & 63;
    int ks   = i >> 9;                             // 0..5
    int k = ks*32 + ((lane >> 4) & 3)*8 + j;
    int n = lane & 15;
    float v = 0.f;
    if (k < 168) {
        int row = k / 24, idx = k % 24;
        if (idx < 21) {
            int kx = idx / 3, ci = idx % 3;
            v = cw[((row*7 + kx)*3 + ci)*16 + n];
        }
    }
    cwb[i] = __float2bfloat16(v);
}

__device__ __forceinline__ void xpad_body(int vb, const float* __restrict__ x,
                                          __hip_bfloat16* __restrict__ xp0,
                                          __hip_bfloat16* __restrict__ xp1)
{
    int idx = vb * 256 + threadIdx.x;              // 5310*256 = 1,359,360 exact
    int e4 = idx % 90;
    int rr = (idx / 90) % 118;
    int fr = idx / (90*118);
    int e0 = e4 * 4;
    int ir = rr - 3;
    const float* xf = x + (size_t)fr * (112*336);
    bool rowok = (ir >= 0) & (ir < 112);

    float v[5];
    #pragma unroll
    for (int i = 0; i < 5; ++i) {
        int s = e0 - 1 + i;
        bool ok = rowok & (s >= 9) & (s < 345);
        v[i] = ok ? xf[ir*336 + (s - 9)] : 0.f;
    }
    size_t o = ((size_t)fr*118 + rr) * XROW + e0;
    uint2 a0, a1;
    a0.x = pk2(v[1], v[2]); a0.y = pk2(v[3], v[4]);
    a1.x = pk2(v[0], v[1]); a1.y = pk2(v[2], v[3]);
    *(uint2*)&xp0[o] = a0;
    *(uint2*)&xp1[o] = a1;
}

// Kernel 0 (R26): ALL independent prep work in ONE dispatch.
// R22/R25 post-mortems pinned ~10us fixed cost per dispatch boundary
// (launch + inter-dispatch L2 coherence on 8 XCDs). xpad + 2 w_prepacks +
// cw_prepack + h0 memset + c0 memset were 6 dispatches; now 1.
// Grid split: [0,5310) xpad | [..+40) wk | [..+40) wr | [..+12) cw |
// [..+365) zero cA (93312 uint4) | [..+183) zero hA (46656 uint4).
__global__ __launch_bounds__(256) void prep_kernel(
    const float* __restrict__ x,
    __hip_bfloat16* __restrict__ xp0, __hip_bfloat16* __restrict__ xp1,
    const float* __restrict__ wk, __hip_bfloat16* __restrict__ wkb,
    const float* __restrict__ wr, __hip_bfloat16* __restrict__ wrb,
    const float* __restrict__ cw, __hip_bfloat16* __restrict__ cwb,
    float* __restrict__ cA, __hip_bfloat16* __restrict__ hA)
{
    int bid = blockIdx.x;
    if (bid < 5310) { xpad_body(bid, x, xp0, xp1); return; }
    bid -= 5310;
    if (bid < 40) { w_prepack_body(bid, wk, wkb); return; }
    bid -= 40;
    if (bid < 40) { w_prepack_body(bid, wr, wrb); return; }
    bid -= 40;
    if (bid < 12) { cw_prepack_body(bid, cw, cwb); return; }
    bid -= 12;
    if (bid < 365) {                               // c0 = 0
        int u = bid*256 + threadIdx.x;
        if (u < 93312) ((uint4*)cA)[u] = (uint4){0,0,0,0};
        return;
    }
    bid -= 365;
    {                                              // h0 = 0
        int u = bid*256 + threadIdx.x;
        if (u < 46656) ((uint4*)hA)[u] = (uint4){0,0,0,0};
    }
}

// Kernel 1: conv 7x7 + bias + relu + maxpool via MFMA.
// R20: LDS-staged input rows (verified win: 47.6 -> ~15 us).
__global__ __launch_bounds__(256, 6) void conv_mfma_kernel(
    const __hip_bfloat16* __restrict__ xp0,
    const __hip_bfloat16* __restrict__ xp1,
    const __hip_bfloat16* __restrict__ cwb,  // [6][64][8]
    const float* __restrict__ cb,            // [16]
    __hip_bfloat16* __restrict__ pooled)     // [128,56,56,16] bf16
{
    int wv = threadIdx.x >> 6;
    int lane = threadIdx.x & 63;
    int quad = lane >> 4;
    int fr = blockIdx.y;
    int p0b = blockIdx.x * 64;               // block's pooled px base
    int p0 = p0b + wv * 16;                  // wave's pooled px base

    // ---- stage: lx[par][10 rows][368 elems] (row padded 360->368) ----
    __shared__ short lx[2][10][368];         // 14,720 B
    int pr0 = p0b / 56;
    int ohb = 2 * pr0;                       // first staged input row
    {
        const __hip_bfloat16* s0 = xp0 + (size_t)fr*XFRM + (size_t)ohb*XROW;
        const __hip_bfloat16* s1 = xp1 + (size_t)fr*XFRM + (size_t)ohb*XROW;
        for (int u = threadIdx.x; u < 900; u += 256) {
            int par = u / 450;
            int rem = u - par*450;
            int rr  = rem / 45;
            int c   = rem - rr*45;           // 16B unit within row
            const __hip_bfloat16* s = (par ? s1 : s0) + rr*XROW + c*8;
            *(uint4*)&lx[par][rr][c*8] = *(const uint4*)s;
        }
    }
    __syncthreads();

    const s8v* wbp = (const s8v*)cwb;
    s8v bfrag[6];
    #pragma unroll
    for (int ks = 0; ks < 6; ++ks) bfrag[ks] = wbp[ks*64 + lane];

    const unsigned* lx32 = (const unsigned*)&lx[0][0][0];

    f4v acc[4];
    #pragma unroll
    for (int j = 0; j < 4; ++j) {
        int mm = lane & 15;
        int pp = p0 + j*4 + (mm >> 2);
        int pos = mm & 3;
        int pr = pp / 56, pc = pp - pr*56;
        int lr = 2*pr - ohb + (pos >> 1);    // 0..3
        int ow = 2*pc + (pos & 1);
        // dword base within lx: parity plane + row + elem offset (always even)
        const unsigned* xr = lx32 + ((ow & 1)*10 + lr)*184 + ((ow*3 + (ow & 1)) >> 1);

        f4v a4 = {0.f,0.f,0.f,0.f};
        #pragma unroll
        for (int ks = 0; ks < 6; ++ks) {
            int blk = ks*4 + quad;
            union { s8v v; unsigned u[4]; } av;
            av.v = (s8v){0,0,0,0,0,0,0,0};
            if (blk < 21) {
                int row = blk / 3;
                int off2 = (blk % 3) * 4;    // dwords
                const unsigned* p = xr + row*184 + off2;
                av.u[0] = p[0]; av.u[1] = p[1]; av.u[2] = p[2]; av.u[3] = p[3];
            }
            a4 = __builtin_amdgcn_mfma_f32_16x16x32_bf16(av.v, bfrag[ks], a4, 0,0,0);
        }
        acc[j] = a4;
    }

    // Epilogue: lane quad owns pooled px p0+j*4+quad, ch nlo; regs = 4 pos.
    int nlo = lane & 15;
    float bias_n = cb[nlo];
    #pragma unroll
    for (int j = 0; j < 4; ++j) {
        float* ap = (float*)&acc[j];
        float mx = fmaxf(fmaxf(ap[0], ap[1]), fmaxf(ap[2], ap[3]));
        float vv = fmaxf(mx + bias_n, 0.f);
        ((unsigned short*)pooled)[((size_t)fr*3136 + p0 + j*4 + quad)*16 + nlo] = f2bfu(vv);
    }
}

// Kernel 2a: zx via MFMA (R14, verified). One wave = 16 pt x 64 gates.
__global__ __launch_bounds__(256, 4) void zx_mfma_kernel(
    const __hip_bfloat16* __restrict__ pooled,  // [128][56][56][16] bf16
    const __hip_bfloat16* __restrict__ wkb,     // [4][5][64][8] bf16
    __hip_bfloat16* __restrict__ zx)            // [64][373248] bf16
{
    int wid  = (blockIdx.x << 2) + (threadIdx.x >> 6);  // 0..23327
    int lane = threadIdx.x & 63;
    int quad = lane >> 4;
    int pt0  = wid << 4;
    int m    = pt0 + (lane & 15);

    int b  = m / (TT*SPIX);
    int rt = m % (TT*SPIX);
    int tt = rt / SPIX;
    int r  = rt % SPIX;
    int oh = r / WO, ow = r % WO;
    const __hip_bfloat16* pf = pooled + (size_t)(b*TT + tt) * (HP*WP*16);

    f4v acc0 = {0.f,0.f,0.f,0.f}, acc1 = acc0, acc2 = acc0, acc3 = acc0;
    const s8v* wb = (const s8v*)wkb;

    #pragma unroll
    for (int ks = 0; ks < 5; ++ks) {
        int blk = ks*4 + quad;
        s8v a;
        if (blk < 18) {
            int tap = blk >> 1, half = blk & 1;
            int ky = tap / 3, kx = tap - ky*3;
            a = *(const s8v*)(pf + ((size_t)(oh+ky)*WP + (ow+kx))*16 + half*8);
        } else {
            a = (s8v){0,0,0,0,0,0,0,0};
        }
        acc0 = __builtin_amdgcn_mfma_f32_16x16x32_bf16(a, wb[(0*5+ks)*64 + lane], acc0, 0,0,0);
        acc1 = __builtin_amdgcn_mfma_f32_16x16x32_bf16(a, wb[(1*5+ks)*64 + lane], acc1, 0,0,0);
        acc2 = __builtin_amdgcn_mfma_f32_16x16x32_bf16(a, wb[(2*5+ks)*64 + lane], acc2, 0,0,0);
        acc3 = __builtin_amdgcn_mfma_f32_16x16x32_bf16(a, wb[(3*5+ks)*64 + lane], acc3, 0,0,0);
    }

    int nlo = lane & 15;
    size_t prow = (size_t)pt0 + quad*4;
    f4v accs[4] = {acc0, acc1, acc2, acc3};
    #pragma unroll
    for (int nt = 0; nt < 4; ++nt) {
        int n = nt*16 + nlo;
        uint2 u;
        u.x = pk2(accs[nt].x, accs[nt].y);
        u.y = pk2(accs[nt].z, accs[nt].w);
        *(uint2*)&zx[(size_t)n * NPT + prow] = u;
    }
}

// Kernel 2b (R26): TWO ConvLSTM steps per dispatch, 1 tile per wave.
// Model (fits R0/R6/R22/R25): step cost = ~10us dispatch boundary + ~0.6us
// per SERIALLY-chained tile per wave. R6 fused 2 steps but serialized 8
// tiles/wave (31us/dispatch). R22/R25: in-kernel cross-XCD coherence is
// ~65-70us/step regardless of sync primitive -> persistent kernels dead.
// This version: 2-row groups (27x8 = 216 blocks), 14 waves/block. Phase A:
// wave w computes ONE tile of h/c_{t+1} over rows y0-1..y0+2 (halo rows
// bit-identical to neighbor blocks' values - R6 verified absmax 0), stash
// h (bf16) + owned-row c (f32) in LDS. Barrier. Phase B: waves 0..6 compute
// ONE tile each of t+2 on the 2 owned rows. 8 dispatches instead of 16,
// ~2 tile-chains of in-kernel latency each.
__global__ __launch_bounds__(896, 4) void lstm_step2(
    const __hip_bfloat16* __restrict__ zx,   // [64][373248]
    const __hip_bfloat16* __restrict__ h_in, // h_t   [8,54,54,16] bf16
    __hip_bfloat16* __restrict__ h_out,      // h_t+2
    const float* __restrict__ cin,           // c_t   [16][23328] planar
    float* __restrict__ cout,                // c_t+2
    const __hip_bfloat16* __restrict__ wrb,  // [4][5][64][8] bf16
    const float* __restrict__ bias,          // [64]
    int t)                                   // even
{
    int g  = blockIdx.x;                     // 0..26 (row pair, y0 = 2g)
    int b  = blockIdx.y;                     // 0..7
    int y0 = 2*g;
    int tid  = threadIdx.x;
    int wv   = tid >> 6;                     // 0..13
    int lane = tid & 63;
    int quad = lane >> 4;
    int ml   = lane & 15;
    int ch   = ml;

    __shared__ __align__(16) short hbuf[4][56][16];  // h_{t+1} rows y0-1..y0+2
    __shared__ float cbuf[2][54][16];                // c_{t+1} owned rows

    // Zero hbuf: unwritten slots (out-of-image rows, ring cols) = SAME-pad 0.
    for (int u = tid; u < 448; u += 896) ((uint4*)hbuf)[u] = (uint4){0,0,0,0};

    const s8v* wbv = (const s8v*)wrb;
    s8v bfr[20];
    #pragma unroll
    for (int i = 0; i < 20; ++i) bfr[i] = wbv[i*64 + lane];

    float b_i = bias[ch], b_f = bias[16+ch], b_g = bias[32+ch], b_o = bias[48+ch];

    const __hip_bfloat16* hb = h_in + (size_t)b * SPIX * 16;
    const unsigned short* zxp = (const unsigned short*)zx;
    size_t zb0 = (size_t)b*(TT*SPIX) + (size_t)t*SPIX;
    size_t zb1 = zb0 + SPIX;

    __syncthreads();                          // hbuf zeros visible

    // ---------------- PHASE A: t -> t+1, rows y0-1..y0+2, 1 tile/wave ----
    {
        int R0a = (y0 - 1) * 54;             // region start (may be <0)
        int ra  = R0a - (R0a & 3);           // align down; covers 224 >= 218
        int pt0 = wv << 4;
        int rm  = ra + pt0 + ml;
        int yA, xA;
        if (rm >= 0) { yA = rm / 54; xA = rm - yA*54; } else { yA = -64; xA = 0; }

        s8v afr[5];
        #pragma unroll
        for (int ks = 0; ks < 5; ++ks) {
            int blk = ks*4 + quad;
            s8v a = (s8v){0,0,0,0,0,0,0,0};
            if (blk < 18) {
                int tap = blk >> 1, half = blk & 1;
                int ky = tap / 3, kx = tap - ky*3;
                int hy = yA + ky - 1, hx = xA + kx - 1;
                if ((hy >= 0) & (hy < HO) & (hx >= 0) & (hx < WO))
                    a = *(const s8v*)(hb + ((size_t)hy*WO + hx)*16 + half*8);
            }
            afr[ks] = a;
        }

        int r0 = ra + pt0 + quad*4;          // multiple of 4
        ushort4 zi, zf, zg_, zo; float4 cold;
        if ((r0 >= 0) && (r0 + 3 < SPIX)) {
            zi  = *(const ushort4*)&zxp[(size_t)( 0+ch)*NPT + zb0 + r0];
            zf  = *(const ushort4*)&zxp[(size_t)(16+ch)*NPT + zb0 + r0];
            zg_ = *(const ushort4*)&zxp[(size_t)(32+ch)*NPT + zb0 + r0];
            zo  = *(const ushort4*)&zxp[(size_t)(48+ch)*NPT + zb0 + r0];
            cold = *(const float4*)&cin[(size_t)ch*NPIX + (size_t)b*SPIX + r0];
        } else {
            unsigned short* zv[4] = {(unsigned short*)&zi, (unsigned short*)&zf,
                                     (unsigned short*)&zg_, (unsigned short*)&zo};
            float* cv = (float*)&cold;
            #pragma unroll
            for (int e = 0; e < 4; ++e) {
                int re = r0 + e;
                bool ok = (re >= 0) & (re < SPIX);
                #pragma unroll
                for (int gg = 0; gg < 4; ++gg)
                    zv[gg][e] = ok ? zxp[(size_t)(gg*16+ch)*NPT + zb0 + re] : 0;
                cv[e] = ok ? cin[(size_t)ch*NPIX + (size_t)b*SPIX + re] : 0.f;
            }
        }

        f4v acc0 = {0.f,0.f,0.f,0.f}, acc1 = acc0, acc2 = acc0, acc3 = acc0;
        #pragma unroll
        for (int ks = 0; ks < 5; ++ks) {
            acc0 = __builtin_amdgcn_mfma_f32_16x16x32_bf16(afr[ks], bfr[0*5+ks], acc0, 0,0,0);
            acc1 = __builtin_amdgcn_mfma_f32_16x16x32_bf16(afr[ks], bfr[1*5+ks], acc1, 0,0,0);
            acc2 = __builtin_amdgcn_mfma_f32_16x16x32_bf16(afr[ks], bfr[2*5+ks], acc2, 0,0,0);
            acc3 = __builtin_amdgcn_mfma_f32_16x16x32_bf16(afr[ks], bfr[3*5+ks], acc3, 0,0,0);
        }

        const unsigned short* zip = (const unsigned short*)&zi;
        const unsigned short* zfp = (const unsigned short*)&zf;
        const unsigned short* zgp = (const unsigned short*)&zg_;
        const unsigned short* zop = (const unsigned short*)&zo;
        float* a0 = (float*)&acc0; float* a1 = (float*)&acc1;
        float* a2 = (float*)&acc2; float* a3 = (float*)&acc3;
        float* co = (float*)&cold;
        #pragma unroll
        for (int reg = 0; reg < 4; ++reg) {
            float iv = hsig (a0[reg] + bf2f(zip[reg]) + b_i);
            float fv = hsig (a1[reg] + bf2f(zfp[reg]) + b_f);
            float gv = tanhf(a2[reg] + bf2f(zgp[reg]) + b_g);
            float ov = hsig (a3[reg] + bf2f(zop[reg]) + b_o);
            float cc = fv * co[reg] + iv * gv;
            float hv = ov * tanhf(cc);
            int rr = r0 + reg;
            if ((rr >= 0) && (rr < SPIX)) {
                int yy = rr / 54, xx = rr - yy*54;
                int lr = yy - (y0 - 1);
                if ((lr >= 0) && (lr < 4)) hbuf[lr][xx+1][ch] = (short)f2bfu(hv);
                int lc = yy - y0;
                if ((lc >= 0) && (lc < 2)) cbuf[lc][xx][ch] = cc;
            }
        }
    }
    __syncthreads();

    // ---------------- PHASE B: t+1 -> t+2, owned rows y0..y0+1 ----------
    if (wv < 7) {
        int rlo = y0*54, rhi = rlo + 108;    // rlo = 108g, multiple of 4
        int pt0 = wv << 4;
        int rm  = rlo + pt0 + ml;
        int yB  = rm / 54, xB = rm - yB*54;  // yB <= y0+2 for pad lanes
        int lrB = yB - y0;

        s8v afr[5];
        #pragma unroll
        for (int ks = 0; ks < 5; ++ks) {
            int blk = ks*4 + quad;
            s8v a = (s8v){0,0,0,0,0,0,0,0};
            if (blk < 18) {
                int tap = blk >> 1, half = blk & 1;
                int ky = tap / 3, kx = tap - ky*3;
                int row = lrB + ky;          // valid lanes: 0..3
                row = row > 3 ? 3 : row;     // pad lanes clamped in-bounds
                a = *(const s8v*)&hbuf[row][xB + kx][half*8];
            }
            afr[ks] = a;
        }

        int r0 = rlo + pt0 + quad*4;
        ushort4 zi, zf, zg_, zo;
        if (r0 + 3 < rhi) {
            zi  = *(const ushort4*)&zxp[(size_t)( 0+ch)*NPT + zb1 + r0];
            zf  = *(const ushort4*)&zxp[(size_t)(16+ch)*NPT + zb1 + r0];
            zg_ = *(const ushort4*)&zxp[(size_t)(32+ch)*NPT + zb1 + r0];
            zo  = *(const ushort4*)&zxp[(size_t)(48+ch)*NPT + zb1 + r0];
        } else {
            unsigned short* zv[4] = {(unsigned short*)&zi, (unsigned short*)&zf,
                                     (unsigned short*)&zg_, (unsigned short*)&zo};
            #pragma unroll
            for (int e = 0; e < 4; ++e) {
                int re = r0 + e;
                bool ok = (re < rhi);
                #pragma unroll
                for (int gg = 0; gg < 4; ++gg)
                    zv[gg][e] = ok ? zxp[(size_t)(gg*16+ch)*NPT + zb1 + re] : 0;
            }
        }

        f4v acc0 = {0.f,0.f,0.f,0.f}, acc1 = acc0, acc2 = acc0, acc3 = acc0;
        #pragma unroll
        for (int ks = 0; ks < 5; ++ks) {
            acc0 = __builtin_amdgcn_mfma_f32_16x16x32_bf16(afr[ks], bfr[0*5+ks], acc0, 0,0,0);
            acc1 = __builtin_amdgcn_mfma_f32_16x16x32_bf16(afr[ks], bfr[1*5+ks], acc1, 0,0,0);
            acc2 = __builtin_amdgcn_mfma_f32_16x16x32_bf16(afr[ks], bfr[2*5+ks], acc2, 0,0,0);
            acc3 = __builtin_amdgcn_mfma_f32_16x16x32_bf16(afr[ks], bfr[3*5+ks], acc3, 0,0,0);
        }

        const unsigned short* zip = (const unsigned short*)&zi;
        const unsigned short* zfp = (const unsigned short*)&zf;
        const unsigned short* zgp = (const unsigned short*)&zg_;
        const unsigned short* zop = (const unsigned short*)&zo;
        float* a0 = (float*)&acc0; float* a1 = (float*)&acc1;
        float* a2 = (float*)&acc2; float* a3 = (float*)&acc3;
        #pragma unroll
        for (int reg = 0; reg < 4; ++reg) {
            int rr = r0 + reg;
            if (rr < rhi) {
                int yy = rr / 54, xx = rr - yy*54;
                float cold = cbuf[yy - y0][xx][ch];
                float iv = hsig (a0[reg] + bf2f(zip[reg]) + b_i);
                float fv = hsig (a1[reg] + bf2f(zfp[reg]) + b_f);
                float gv = tanhf(a2[reg] + bf2f(zgp[reg]) + b_g);
                float ov = hsig (a3[reg] + bf2f(zop[reg]) + b_o);
                float cc = fv * cold + iv * gv;
                float hv = ov * tanhf(cc);
                cout[(size_t)ch*NPIX + (size_t)b*SPIX + rr] = cc;
                ((unsigned short*)h_out)[((size_t)b*SPIX + rr)*16 + ch] = f2bfu(hv);
            }
        }
    }
}

// Kernel 3: spatial mean (bf16 h) -> dense(16->6) -> softmax. One block per b.
// R18: short8 loads, 1024 threads, parity-preserving LDS tree (verified win).
__global__ __launch_bounds__(1024) void head_kernel(
    const __hip_bfloat16* __restrict__ h,   // [8,54,54,16] bf16
    const float* __restrict__ dw,   // [16,6]
    const float* __restrict__ db,   // [6]
    float* __restrict__ out)        // [8,6]
{
    int b = blockIdx.x;
    int tid = threadIdx.x;
    const s8v* hb = (const s8v*)(h + (size_t)b * SPIX * 16);  // 5832 s8v per b

    float acc[8] = {0.f,0.f,0.f,0.f,0.f,0.f,0.f,0.f};
    for (int j = tid; j < SPIX*2; j += 1024) {
        s8v v = hb[j];
        #pragma unroll
        for (int k = 0; k < 8; ++k) acc[k] += bf2f((unsigned short)v[k]);
    }

    __shared__ float red[1024][8];           // 32 KB
    #pragma unroll
    for (int k = 0; k < 8; ++k) red[tid][k] = acc[k];
    __syncthreads();
    for (int st = 512; st >= 2; st >>= 1) {
        if (tid < st) {
            #pragma unroll
            for (int k = 0; k < 8; ++k) red[tid][k] += red[tid + st][k];
        }
        __syncthreads();
    }

    __shared__ float logits[8];
    if (tid < NC) {
        float l = db[tid];
        #pragma unroll
        for (int k = 0; k < 8; ++k) {
            l += (red[0][k] * (1.0f/2916.0f)) * dw[k*NC + tid];
            l += (red[1][k] * (1.0f/2916.0f)) * dw[(8+k)*NC + tid];
        }
        logits[tid] = l;
    }
    __syncthreads();
    if (tid < NC) {
        float m = -1e30f;
        for (int k = 0; k < NC; ++k) m = fmaxf(m, logits[k]);
        float e = expf(logits[tid] - m);
        float d = 0.0f;
        for (int k = 0; k < NC; ++k) d += expf(logits[k] - m);
        out[b*NC + tid] = e / d;
    }
}

extern "C" void kernel_launch(void* const* d_in, const int* in_sizes, int n_in,
                              void* d_out, int out_size, void* d_ws, size_t ws_size,
                              hipStream_t stream) {
    const float* x      = (const float*)d_in[0];
    const float* conv_w = (const float*)d_in[1];
    const float* conv_b = (const float*)d_in[2];
    const float* wk     = (const float*)d_in[3];
    const float* wr     = (const float*)d_in[4];
    const float* bias   = (const float*)d_in[5];
    const float* dw     = (const float*)d_in[6];
    const float* db     = (const float*)d_in[7];
    float* out = (float*)d_out;

    char* base = (char*)d_ws;
    __hip_bfloat16* pooled = (__hip_bfloat16*)base;                 // 12.85 MB
    __hip_bfloat16* hA  = pooled + POOLED_BF16;                     // 746 KB
    __hip_bfloat16* hB  = hA + NPIX*16;
    __hip_bfloat16* wkb = hB + NPIX*16;                             // 20 KB
    __hip_bfloat16* wrb = wkb + 10240;                              // 20 KB
    __hip_bfloat16* cwb = wrb + 10240;                              // 6 KB
    float* cA = (float*)(cwb + 3072);                               // 1.49 MB
    float* cB = cA + NPIX*16;                                       // 1.49 MB
    __hip_bfloat16* zx  = (__hip_bfloat16*)(cB + NPIX*16);          // 47.8 MB
    // xpad parity copies ALIAS zx (consumed before zx is written).
    __hip_bfloat16* xp0 = zx;
    __hip_bfloat16* xp1 = zx + XPAD_ELEMS;

    // One prep dispatch: xpad + wk/wr/cw prepack + c0/h0 zero.
    prep_kernel<<<dim3(5950), dim3(256), 0, stream>>>(
        x, xp0, xp1, wk, wkb, wr, wrb, conv_w, cwb, cA, hA);
    conv_mfma_kernel<<<dim3(49, 128), dim3(256), 0, stream>>>(xp0, xp1, cwb, conv_b, pooled);
    zx_mfma_kernel<<<dim3(5832), dim3(256), 0, stream>>>(pooled, wkb, zx);

    // 8 dispatches, 2 time-steps each, 1 tile per wave per phase.
    for (int k = 0; k < 8; ++k) {
        const __hip_bfloat16* hin  = (k & 1) ? hB : hA;
        __hip_bfloat16*       hout = (k & 1) ? hA : hB;
        const float* ci = (k & 1) ? cB : cA;
        float*       co = (k & 1) ? cA : cB;
        lstm_step2<<<dim3(27, 8), dim3(896), 0, stream>>>(
            zx, hin, hout, ci, co, wrb, bias, 2*k);
    }
    // k=7 wrote hA (h16)
    head_kernel<<<dim3(8), dim3(1024), 0, stream>>>(hA, dw, db, out);
}

// Round 10
// 249.390 us; speedup vs baseline: 5.1231x; 1.2543x over previous
//
#include <hip/hip_runtime.h>
#include <hip/hip_bf16.h>
#include <math.h>

// Problem dims
#define BB 8
#define TT 16
#define HH 112
#define WW 112
#define CC 3
#define FF 16
#define HP 56
#define WP 56
#define HO 54
#define WO 54
#define NC 6

#define NPIX (BB*HO*WO)               // 23328
#define SPIX (HO*WO)                  // 2916
#define NPT  (BB*TT*SPIX)             // 373248  (b,t,pixel)
#define POOLED_BF16  (128*56*56*16)   // 6,422,528 bf16

// xpad: per-frame bf16 rows with halo + pad: 118 rows x 360 elems
#define XROW 360
#define XFRM (118*XROW)               // 42,480
#define XPAD_ELEMS (128*XFRM)         // 5,437,440 per parity copy

typedef __attribute__((ext_vector_type(8))) short s8v;   // 8 bf16 (4 VGPRs)
typedef __attribute__((ext_vector_type(4))) float f4v;   // MFMA acc

__device__ __forceinline__ float hsig(float x) {
    return fminf(fmaxf(0.2f*x + 0.5f, 0.0f), 1.0f);
}
__device__ __forceinline__ unsigned pk2(float lo, float hi) {
    union { __hip_bfloat16 h; unsigned short u; } a, b;
    a.h = __float2bfloat16(lo); b.h = __float2bfloat16(hi);
    return ((unsigned)b.u << 16) | (unsigned)a.u;
}
__device__ __forceinline__ float bf2f(unsigned short u) {
    union { unsigned v; float f; } x; x.v = ((unsigned)u) << 16; return x.f;
}
__device__ __forceinline__ unsigned short f2bfu(float f) {
    union { __hip_bfloat16 h; unsigned short u; } v;
    v.h = __float2bfloat16(f); return v.u;
}

// ---------- prep job bodies (verbatim logic, virtual block id) ----------
__device__ __forceinline__ void w_prepack_body(int vb, const float* __restrict__ w,
                                               __hip_bfloat16* __restrict__ wb)
{
    int i = vb * 256 + threadIdx.x;                // 40*256 = 10240 exact
    int j    = i & 7;
    int lane = (i >> 3) & 63;
    int ks   = (i >> 9) % 5;
    int nt   = (i >> 9) / 5;
    int k = ks*32 + ((lane >> 4) & 3)*8 + j;
    int n = nt*16 + (lane & 15);
    float v = 0.f;
    if (k < 144) {
        int tap = k >> 4, ci = k & 15;
        v = w[tap*1024 + ci*64 + n];
    }
    wb[i] = __float2bfloat16(v);
}

__device__ __forceinline__ void cw_prepack_body(int vb, const float* __restrict__ cw,
                                                __hip_bfloat16* __restrict__ cwb)
{
    int i = vb * 256 + threadIdx.x;                // 12*256 = 3072 exact
    int j    = i & 7;
    int lane = (i >> 3) & 63;
    int ks   = i >> 9;                             // 0..5
    int k = ks*32 + ((lane >> 4) & 3)*8 + j;
    int n = lane & 15;
    float v = 0.f;
    if (k < 168) {
        int row = k / 24, idx = k % 24;
        if (idx < 21) {
            int kx = idx / 3, ci = idx % 3;
            v = cw[((row*7 + kx)*3 + ci)*16 + n];
        }
    }
    cwb[i] = __float2bfloat16(v);
}

__device__ __forceinline__ void xpad_body(int vb, const float* __restrict__ x,
                                          __hip_bfloat16* __restrict__ xp0,
                                          __hip_bfloat16* __restrict__ xp1)
{
    int idx = vb * 256 + threadIdx.x;              // 5310*256 = 1,359,360 exact
    int e4 = idx % 90;
    int rr = (idx / 90) % 118;
    int fr = idx / (90*118);
    int e0 = e4 * 4;
    int ir = rr - 3;
    const float* xf = x + (size_t)fr * (112*336);
    bool rowok = (ir >= 0) & (ir < 112);

    float v[5];
    #pragma unroll
    for (int i = 0; i < 5; ++i) {
        int s = e0 - 1 + i;
        bool ok = rowok & (s >= 9) & (s < 345);
        v[i] = ok ? xf[ir*336 + (s - 9)] : 0.f;
    }
    size_t o = ((size_t)fr*118 + rr) * XROW + e0;
    uint2 a0, a1;
    a0.x = pk2(v[1], v[2]); a0.y = pk2(v[3], v[4]);
    a1.x = pk2(v[0], v[1]); a1.y = pk2(v[2], v[3]);
    *(uint2*)&xp0[o] = a0;
    *(uint2*)&xp1[o] = a1;
}

// Kernel 0 (R26, kept): ALL independent prep work in ONE dispatch.
// Grid split: [0,5310) xpad | [..+40) wk | [..+40) wr | [..+12) cw |
// [..+365) zero cpl (93312 uint4) | [..+183) zero hA (46656 uint4).
__global__ __launch_bounds__(256) void prep_kernel(
    const float* __restrict__ x,
    __hip_bfloat16* __restrict__ xp0, __hip_bfloat16* __restrict__ xp1,
    const float* __restrict__ wk, __hip_bfloat16* __restrict__ wkb,
    const float* __restrict__ wr, __hip_bfloat16* __restrict__ wrb,
    const float* __restrict__ cw, __hip_bfloat16* __restrict__ cwb,
    float* __restrict__ cpl, __hip_bfloat16* __restrict__ hA)
{
    int bid = blockIdx.x;
    if (bid < 5310) { xpad_body(bid, x, xp0, xp1); return; }
    bid -= 5310;
    if (bid < 40) { w_prepack_body(bid, wk, wkb); return; }
    bid -= 40;
    if (bid < 40) { w_prepack_body(bid, wr, wrb); return; }
    bid -= 40;
    if (bid < 12) { cw_prepack_body(bid, cw, cwb); return; }
    bid -= 12;
    if (bid < 365) {                               // c0 = 0
        int u = bid*256 + threadIdx.x;
        if (u < 93312) ((uint4*)cpl)[u] = (uint4){0,0,0,0};
        return;
    }
    bid -= 365;
    {                                              // h0 = 0
        int u = bid*256 + threadIdx.x;
        if (u < 46656) ((uint4*)hA)[u] = (uint4){0,0,0,0};
    }
}

// Kernel 1: conv 7x7 + bias + relu + maxpool via MFMA.
// R20: LDS-staged input rows (verified win: 47.6 -> ~15 us).
__global__ __launch_bounds__(256, 6) void conv_mfma_kernel(
    const __hip_bfloat16* __restrict__ xp0,
    const __hip_bfloat16* __restrict__ xp1,
    const __hip_bfloat16* __restrict__ cwb,  // [6][64][8]
    const float* __restrict__ cb,            // [16]
    __hip_bfloat16* __restrict__ pooled)     // [128,56,56,16] bf16
{
    int wv = threadIdx.x >> 6;
    int lane = threadIdx.x & 63;
    int quad = lane >> 4;
    int fr = blockIdx.y;
    int p0b = blockIdx.x * 64;               // block's pooled px base
    int p0 = p0b + wv * 16;                  // wave's pooled px base

    // ---- stage: lx[par][10 rows][368 elems] (row padded 360->368) ----
    __shared__ short lx[2][10][368];         // 14,720 B
    int pr0 = p0b / 56;
    int ohb = 2 * pr0;                       // first staged input row
    {
        const __hip_bfloat16* s0 = xp0 + (size_t)fr*XFRM + (size_t)ohb*XROW;
        const __hip_bfloat16* s1 = xp1 + (size_t)fr*XFRM + (size_t)ohb*XROW;
        for (int u = threadIdx.x; u < 900; u += 256) {
            int par = u / 450;
            int rem = u - par*450;
            int rr  = rem / 45;
            int c   = rem - rr*45;           // 16B unit within row
            const __hip_bfloat16* s = (par ? s1 : s0) + rr*XROW + c*8;
            *(uint4*)&lx[par][rr][c*8] = *(const uint4*)s;
        }
    }
    __syncthreads();

    const s8v* wbp = (const s8v*)cwb;
    s8v bfrag[6];
    #pragma unroll
    for (int ks = 0; ks < 6; ++ks) bfrag[ks] = wbp[ks*64 + lane];

    const unsigned* lx32 = (const unsigned*)&lx[0][0][0];

    f4v acc[4];
    #pragma unroll
    for (int j = 0; j < 4; ++j) {
        int mm = lane & 15;
        int pp = p0 + j*4 + (mm >> 2);
        int pos = mm & 3;
        int pr = pp / 56, pc = pp - pr*56;
        int lr = 2*pr - ohb + (pos >> 1);    // 0..3
        int ow = 2*pc + (pos & 1);
        // dword base within lx: parity plane + row + elem offset (always even)
        const unsigned* xr = lx32 + ((ow & 1)*10 + lr)*184 + ((ow*3 + (ow & 1)) >> 1);

        f4v a4 = {0.f,0.f,0.f,0.f};
        #pragma unroll
        for (int ks = 0; ks < 6; ++ks) {
            int blk = ks*4 + quad;
            union { s8v v; unsigned u[4]; } av;
            av.v = (s8v){0,0,0,0,0,0,0,0};
            if (blk < 21) {
                int row = blk / 3;
                int off2 = (blk % 3) * 4;    // dwords
                const unsigned* p = xr + row*184 + off2;
                av.u[0] = p[0]; av.u[1] = p[1]; av.u[2] = p[2]; av.u[3] = p[3];
            }
            a4 = __builtin_amdgcn_mfma_f32_16x16x32_bf16(av.v, bfrag[ks], a4, 0,0,0);
        }
        acc[j] = a4;
    }

    // Epilogue: lane quad owns pooled px p0+j*4+quad, ch nlo; regs = 4 pos.
    int nlo = lane & 15;
    float bias_n = cb[nlo];
    #pragma unroll
    for (int j = 0; j < 4; ++j) {
        float* ap = (float*)&acc[j];
        float mx = fmaxf(fmaxf(ap[0], ap[1]), fmaxf(ap[2], ap[3]));
        float vv = fmaxf(mx + bias_n, 0.f);
        ((unsigned short*)pooled)[((size_t)fr*3136 + p0 + j*4 + quad)*16 + nlo] = f2bfu(vv);
    }
}

// Kernel 2a: zx via MFMA (R14, verified). One wave = 16 pt x 64 gates.
__global__ __launch_bounds__(256, 4) void zx_mfma_kernel(
    const __hip_bfloat16* __restrict__ pooled,  // [128][56][56][16] bf16
    const __hip_bfloat16* __restrict__ wkb,     // [4][5][64][8] bf16
    __hip_bfloat16* __restrict__ zx)            // [64][373248] bf16
{
    int wid  = (blockIdx.x << 2) + (threadIdx.x >> 6);  // 0..23327
    int lane = threadIdx.x & 63;
    int quad = lane >> 4;
    int pt0  = wid << 4;
    int m    = pt0 + (lane & 15);

    int b  = m / (TT*SPIX);
    int rt = m % (TT*SPIX);
    int tt = rt / SPIX;
    int r  = rt % SPIX;
    int oh = r / WO, ow = r % WO;
    const __hip_bfloat16* pf = pooled + (size_t)(b*TT + tt) * (HP*WP*16);

    f4v acc0 = {0.f,0.f,0.f,0.f}, acc1 = acc0, acc2 = acc0, acc3 = acc0;
    const s8v* wb = (const s8v*)wkb;

    #pragma unroll
    for (int ks = 0; ks < 5; ++ks) {
        int blk = ks*4 + quad;
        s8v a;
        if (blk < 18) {
            int tap = blk >> 1, half = blk & 1;
            int ky = tap / 3, kx = tap - ky*3;
            a = *(const s8v*)(pf + ((size_t)(oh+ky)*WP + (ow+kx))*16 + half*8);
        } else {
            a = (s8v){0,0,0,0,0,0,0,0};
        }
        acc0 = __builtin_amdgcn_mfma_f32_16x16x32_bf16(a, wb[(0*5+ks)*64 + lane], acc0, 0,0,0);
        acc1 = __builtin_amdgcn_mfma_f32_16x16x32_bf16(a, wb[(1*5+ks)*64 + lane], acc1, 0,0,0);
        acc2 = __builtin_amdgcn_mfma_f32_16x16x32_bf16(a, wb[(2*5+ks)*64 + lane], acc2, 0,0,0);
        acc3 = __builtin_amdgcn_mfma_f32_16x16x32_bf16(a, wb[(3*5+ks)*64 + lane], acc3, 0,0,0);
    }

    int nlo = lane & 15;
    size_t prow = (size_t)pt0 + quad*4;
    f4v accs[4] = {acc0, acc1, acc2, acc3};
    #pragma unroll
    for (int nt = 0; nt < 4; ++nt) {
        int n = nt*16 + nlo;
        uint2 u;
        u.x = pk2(accs[nt].x, accs[nt].y);
        u.y = pk2(accs[nt].z, accs[nt].w);
        *(uint2*)&zx[(size_t)n * NPT + prow] = u;
    }
}

// Kernel 2b: one ConvLSTM step via MFMA — EXACT R3-best kernel (16 launches,
// 365x4-wave blocks) with ONE change (R27): __launch_bounds__(256,4)->(256,2).
// Theory: R7's counter row showed VGPR_Count=84 for a kernel whose working
// set (20 B-frag s8v = 80 VGPR + 18 A-frag + 16 acc) needs 164+ — at the
// 128-VGPR cap the compiler re-loads B-frags from global INSIDE the MFMA
// chain, serializing ~35-40 x ~650cy L2/L3 round trips = 24k cy/tile, which
// matches the measured 10us/1458-tile step exactly. (256,2) raises the cap
// to 256 so all fragments stay resident; actual occupancy (5.7 waves/CU)
// is unaffected. Single-variable test of the serialization theory.
__global__ __launch_bounds__(256, 2) void lstm_step_mfma(
    const __hip_bfloat16* __restrict__ zx,   // [64][373248]
    const __hip_bfloat16* __restrict__ h_in, // [8,54,54,16] bf16
    __hip_bfloat16* __restrict__ h_out,
    float* __restrict__ cpl,                 // [16][23328] planar fp32
    const __hip_bfloat16* __restrict__ wrb,  // [4][5][64][8] bf16
    const float* __restrict__ bias,          // [64]
    int t)
{
    int wid = (blockIdx.x << 2) + (threadIdx.x >> 6);
    if (wid >= 1458) return;                 // no barriers below
    int lane = threadIdx.x & 63;
    int quad = lane >> 4;
    int pt0  = wid << 4;
    int m    = pt0 + (lane & 15);

    int b  = m / SPIX;
    int r  = m % SPIX;
    int oh = r / WO, ow = r % WO;
    const __hip_bfloat16* hb = h_in + (size_t)b * SPIX * 16;

    f4v acc0 = {0.f,0.f,0.f,0.f}, acc1 = acc0, acc2 = acc0, acc3 = acc0;
    const s8v* wb = (const s8v*)wrb;

    #pragma unroll
    for (int ks = 0; ks < 5; ++ks) {
        int blk = ks*4 + quad;
        s8v a = (s8v){0,0,0,0,0,0,0,0};
        if (blk < 18) {
            int tap = blk >> 1, half = blk & 1;
            int ky = tap / 3, kx = tap - ky*3;
            int hy = oh + ky - 1, hx = ow + kx - 1;   // SAME pad
            if ((hy >= 0) & (hy < HO) & (hx >= 0) & (hx < WO))
                a = *(const s8v*)(hb + ((size_t)hy*WO + hx)*16 + half*8);
        }
        acc0 = __builtin_amdgcn_mfma_f32_16x16x32_bf16(a, wb[(0*5+ks)*64 + lane], acc0, 0,0,0);
        acc1 = __builtin_amdgcn_mfma_f32_16x16x32_bf16(a, wb[(1*5+ks)*64 + lane], acc1, 0,0,0);
        acc2 = __builtin_amdgcn_mfma_f32_16x16x32_bf16(a, wb[(2*5+ks)*64 + lane], acc2, 0,0,0);
        acc3 = __builtin_amdgcn_mfma_f32_16x16x32_bf16(a, wb[(3*5+ks)*64 + lane], acc3, 0,0,0);
    }

    // Epilogue: lane owns channel ch for pixels pm..pm+3 (one b: 2916%4==0).
    int ch = lane & 15;
    int pm = pt0 + quad*4;
    int b2 = pm / SPIX, r2 = pm % SPIX;
    size_t ptz = (size_t)b2 * (TT*SPIX) + (size_t)t * SPIX + r2;

    ushort4 zi = *(const ushort4*)&zx[(size_t)( 0 + ch) * NPT + ptz];
    ushort4 zf = *(const ushort4*)&zx[(size_t)(16 + ch) * NPT + ptz];
    ushort4 zg = *(const ushort4*)&zx[(size_t)(32 + ch) * NPT + ptz];
    ushort4 zo = *(const ushort4*)&zx[(size_t)(48 + ch) * NPT + ptz];

    float4 cold = *(float4*)&cpl[(size_t)ch * NPIX + pm];
    float b_i = bias[ch], b_f = bias[16+ch], b_g = bias[32+ch], b_o = bias[48+ch];

    float4 cnew;
    unsigned short hn[4];
    float* co = &cold.x; float* cn = &cnew.x;
    const unsigned short* zip = (const unsigned short*)&zi;
    const unsigned short* zfp = (const unsigned short*)&zf;
    const unsigned short* zgp = (const unsigned short*)&zg;
    const unsigned short* zop = (const unsigned short*)&zo;
    float* a0 = (float*)&acc0; float* a1 = (float*)&acc1;
    float* a2 = (float*)&acc2; float* a3 = (float*)&acc3;
    #pragma unroll
    for (int reg = 0; reg < 4; ++reg) {
        float iv = hsig (a0[reg] + bf2f(zip[reg]) + b_i);
        float fv = hsig (a1[reg] + bf2f(zfp[reg]) + b_f);
        float gv = tanhf(a2[reg] + bf2f(zgp[reg]) + b_g);
        float ov = hsig (a3[reg] + bf2f(zop[reg]) + b_o);
        float cc = fv * co[reg] + iv * gv;
        cn[reg] = cc;
        hn[reg] = f2bfu(ov * tanhf(cc));
    }
    *(float4*)&cpl[(size_t)ch * NPIX + pm] = cnew;
    #pragma unroll
    for (int reg = 0; reg < 4; ++reg)
        ((unsigned short*)h_out)[(size_t)(pm + reg) * 16 + ch] = hn[reg];
}

// Kernel 3: spatial mean (bf16 h) -> dense(16->6) -> softmax. One block per b.
// R18: short8 loads, 1024 threads, parity-preserving LDS tree (verified win).
__global__ __launch_bounds__(1024) void head_kernel(
    const __hip_bfloat16* __restrict__ h,   // [8,54,54,16] bf16
    const float* __restrict__ dw,   // [16,6]
    const float* __restrict__ db,   // [6]
    float* __restrict__ out)        // [8,6]
{
    int b = blockIdx.x;
    int tid = threadIdx.x;
    const s8v* hb = (const s8v*)(h + (size_t)b * SPIX * 16);  // 5832 s8v per b

    float acc[8] = {0.f,0.f,0.f,0.f,0.f,0.f,0.f,0.f};
    for (int j = tid; j < SPIX*2; j += 1024) {
        s8v v = hb[j];
        #pragma unroll
        for (int k = 0; k < 8; ++k) acc[k] += bf2f((unsigned short)v[k]);
    }

    __shared__ float red[1024][8];           // 32 KB
    #pragma unroll
    for (int k = 0; k < 8; ++k) red[tid][k] = acc[k];
    __syncthreads();
    for (int st = 512; st >= 2; st >>= 1) {
        if (tid < st) {
            #pragma unroll
            for (int k = 0; k < 8; ++k) red[tid][k] += red[tid + st][k];
        }
        __syncthreads();
    }

    __shared__ float logits[8];
    if (tid < NC) {
        float l = db[tid];
        #pragma unroll
        for (int k = 0; k < 8; ++k) {
            l += (red[0][k] * (1.0f/2916.0f)) * dw[k*NC + tid];
            l += (red[1][k] * (1.0f/2916.0f)) * dw[(8+k)*NC + tid];
        }
        logits[tid] = l;
    }
    __syncthreads();
    if (tid < NC) {
        float m = -1e30f;
        for (int k = 0; k < NC; ++k) m = fmaxf(m, logits[k]);
        float e = expf(logits[tid] - m);
        float d = 0.0f;
        for (int k = 0; k < NC; ++k) d += expf(logits[k] - m);
        out[b*NC + tid] = e / d;
    }
}

extern "C" void kernel_launch(void* const* d_in, const int* in_sizes, int n_in,
                              void* d_out, int out_size, void* d_ws, size_t ws_size,
                              hipStream_t stream) {
    const float* x      = (const float*)d_in[0];
    const float* conv_w = (const float*)d_in[1];
    const float* conv_b = (const float*)d_in[2];
    const float* wk     = (const float*)d_in[3];
    const float* wr     = (const float*)d_in[4];
    const float* bias   = (const float*)d_in[5];
    const float* dw     = (const float*)d_in[6];
    const float* db     = (const float*)d_in[7];
    float* out = (float*)d_out;

    char* base = (char*)d_ws;
    __hip_bfloat16* pooled = (__hip_bfloat16*)base;                 // 12.85 MB
    __hip_bfloat16* hA  = pooled + POOLED_BF16;                     // 746 KB
    __hip_bfloat16* hB  = hA + NPIX*16;
    __hip_bfloat16* wkb = hB + NPIX*16;                             // 20 KB
    __hip_bfloat16* wrb = wkb + 10240;                              // 20 KB
    __hip_bfloat16* cwb = wrb + 10240;                              // 6 KB
    float* cpl = (float*)(cwb + 3072);                              // 1.49 MB
    __hip_bfloat16* zx  = (__hip_bfloat16*)(cpl + NPIX*16);         // 47.8 MB
    // xpad parity copies ALIAS zx (consumed before zx is written).
    __hip_bfloat16* xp0 = zx;
    __hip_bfloat16* xp1 = zx + XPAD_ELEMS;

    // One prep dispatch: xpad + wk/wr/cw prepack + c0/h0 zero.
    prep_kernel<<<dim3(5950), dim3(256), 0, stream>>>(
        x, xp0, xp1, wk, wkb, wr, wrb, conv_w, cwb, cpl, hA);
    conv_mfma_kernel<<<dim3(49, 128), dim3(256), 0, stream>>>(xp0, xp1, cwb, conv_b, pooled);
    zx_mfma_kernel<<<dim3(5832), dim3(256), 0, stream>>>(pooled, wkb, zx);

    for (int t = 0; t < TT; ++t) {
        const __hip_bfloat16* hin  = (t & 1) ? hB : hA;
        __hip_bfloat16*       hout = (t & 1) ? hA : hB;
        lstm_step_mfma<<<dim3(365), dim3(256), 0, stream>>>(
            zx, hin, hout, cpl, wrb, bias, t);
    }
    // t=15 (odd) wrote hA
    head_kernel<<<dim3(8), dim3(1024), 0, stream>>>(hA, dw, db, out);
}

// Round 11
// 248.140 us; speedup vs baseline: 5.1489x; 1.0050x over previous
//
#include <hip/hip_runtime.h>
#include <hip/hip_bf16.h>
#include <math.h>

// Problem dims
#define BB 8
#define TT 16
#define HH 112
#define WW 112
#define CC 3
#define FF 16
#define HP 56
#define WP 56
#define HO 54
#define WO 54
#define NC 6

#define NPIX (BB*HO*WO)               // 23328
#define SPIX (HO*WO)                  // 2916
#define NPT  (BB*TT*SPIX)             // 373248  (b,t,pixel)
#define POOLED_BF16  (128*56*56*16)   // 6,422,528 bf16

// xpad: per-frame bf16 rows with halo + pad: 118 rows x 360 elems
#define XROW 360
#define XFRM (118*XROW)               // 42,480
#define XPAD_ELEMS (128*XFRM)         // 5,437,440 per parity copy

typedef __attribute__((ext_vector_type(8))) short s8v;   // 8 bf16 (4 VGPRs)
typedef __attribute__((ext_vector_type(4))) float f4v;   // MFMA acc

__device__ __forceinline__ float hsig(float x) {
    return fminf(fmaxf(0.2f*x + 0.5f, 0.0f), 1.0f);
}
__device__ __forceinline__ unsigned pk2(float lo, float hi) {
    union { __hip_bfloat16 h; unsigned short u; } a, b;
    a.h = __float2bfloat16(lo); b.h = __float2bfloat16(hi);
    return ((unsigned)b.u << 16) | (unsigned)a.u;
}
__device__ __forceinline__ float bf2f(unsigned short u) {
    union { unsigned v; float f; } x; x.v = ((unsigned)u) << 16; return x.f;
}
__device__ __forceinline__ unsigned short f2bfu(float f) {
    union { __hip_bfloat16 h; unsigned short u; } v;
    v.h = __float2bfloat16(f); return v.u;
}

// ---------- prep job bodies (verbatim logic, virtual block id) ----------
__device__ __forceinline__ void w_prepack_body(int vb, const float* __restrict__ w,
                                               __hip_bfloat16* __restrict__ wb)
{
    int i = vb * 256 + threadIdx.x;                // 40*256 = 10240 exact
    int j    = i & 7;
    int lane = (i >> 3) & 63;
    int ks   = (i >> 9) % 5;
    int nt   = (i >> 9) / 5;
    int k = ks*32 + ((lane >> 4) & 3)*8 + j;
    int n = nt*16 + (lane & 15);
    float v = 0.f;
    if (k < 144) {
        int tap = k >> 4, ci = k & 15;
        v = w[tap*1024 + ci*64 + n];
    }
    wb[i] = __float2bfloat16(v);
}

__device__ __forceinline__ void cw_prepack_body(int vb, const float* __restrict__ cw,
                                                __hip_bfloat16* __restrict__ cwb)
{
    int i = vb * 256 + threadIdx.x;                // 12*256 = 3072 exact
    int j    = i & 7;
    int lane = (i >> 3) & 63;
    int ks   = i >> 9;                             // 0..5
    int k = ks*32 + ((lane >> 4) & 3)*8 + j;
    int n = lane & 15;
    float v = 0.f;
    if (k < 168) {
        int row = k / 24, idx = k % 24;
        if (idx < 21) {
            int kx = idx / 3, ci = idx % 3;
            v = cw[((row*7 + kx)*3 + ci)*16 + n];
        }
    }
    cwb[i] = __float2bfloat16(v);
}

__device__ __forceinline__ void xpad_body(int vb, const float* __restrict__ x,
                                          __hip_bfloat16* __restrict__ xp0,
                                          __hip_bfloat16* __restrict__ xp1)
{
    int idx = vb * 256 + threadIdx.x;              // 5310*256 = 1,359,360 exact
    int e4 = idx % 90;
    int rr = (idx / 90) % 118;
    int fr = idx / (90*118);
    int e0 = e4 * 4;
    int ir = rr - 3;
    const float* xf = x + (size_t)fr * (112*336);
    bool rowok = (ir >= 0) & (ir < 112);

    float v[5];
    #pragma unroll
    for (int i = 0; i < 5; ++i) {
        int s = e0 - 1 + i;
        bool ok = rowok & (s >= 9) & (s < 345);
        v[i] = ok ? xf[ir*336 + (s - 9)] : 0.f;
    }
    size_t o = ((size_t)fr*118 + rr) * XROW + e0;
    uint2 a0, a1;
    a0.x = pk2(v[1], v[2]); a0.y = pk2(v[3], v[4]);
    a1.x = pk2(v[0], v[1]); a1.y = pk2(v[2], v[3]);
    *(uint2*)&xp0[o] = a0;
    *(uint2*)&xp1[o] = a1;
}

// Kernel 0 (R26, kept): ALL independent prep work in ONE dispatch.
// Grid split: [0,5310) xpad | [..+40) wk | [..+40) wr | [..+12) cw |
// [..+365) zero cpl (93312 uint4) | [..+183) zero hA (46656 uint4).
__global__ __launch_bounds__(256) void prep_kernel(
    const float* __restrict__ x,
    __hip_bfloat16* __restrict__ xp0, __hip_bfloat16* __restrict__ xp1,
    const float* __restrict__ wk, __hip_bfloat16* __restrict__ wkb,
    const float* __restrict__ wr, __hip_bfloat16* __restrict__ wrb,
    const float* __restrict__ cw, __hip_bfloat16* __restrict__ cwb,
    float* __restrict__ cpl, __hip_bfloat16* __restrict__ hA)
{
    int bid = blockIdx.x;
    if (bid < 5310) { xpad_body(bid, x, xp0, xp1); return; }
    bid -= 5310;
    if (bid < 40) { w_prepack_body(bid, wk, wkb); return; }
    bid -= 40;
    if (bid < 40) { w_prepack_body(bid, wr, wrb); return; }
    bid -= 40;
    if (bid < 12) { cw_prepack_body(bid, cw, cwb); return; }
    bid -= 12;
    if (bid < 365) {                               // c0 = 0
        int u = bid*256 + threadIdx.x;
        if (u < 93312) ((uint4*)cpl)[u] = (uint4){0,0,0,0};
        return;
    }
    bid -= 365;
    {                                              // h0 = 0
        int u = bid*256 + threadIdx.x;
        if (u < 46656) ((uint4*)hA)[u] = (uint4){0,0,0,0};
    }
}

// Kernel 1: conv 7x7 + bias + relu + maxpool via MFMA.
// R20: LDS-staged input rows (verified win: 47.6 -> ~15 us).
__global__ __launch_bounds__(256, 6) void conv_mfma_kernel(
    const __hip_bfloat16* __restrict__ xp0,
    const __hip_bfloat16* __restrict__ xp1,
    const __hip_bfloat16* __restrict__ cwb,  // [6][64][8]
    const float* __restrict__ cb,            // [16]
    __hip_bfloat16* __restrict__ pooled)     // [128,56,56,16] bf16
{
    int wv = threadIdx.x >> 6;
    int lane = threadIdx.x & 63;
    int quad = lane >> 4;
    int fr = blockIdx.y;
    int p0b = blockIdx.x * 64;               // block's pooled px base
    int p0 = p0b + wv * 16;                  // wave's pooled px base

    // ---- stage: lx[par][10 rows][368 elems] (row padded 360->368) ----
    __shared__ short lx[2][10][368];         // 14,720 B
    int pr0 = p0b / 56;
    int ohb = 2 * pr0;                       // first staged input row
    {
        const __hip_bfloat16* s0 = xp0 + (size_t)fr*XFRM + (size_t)ohb*XROW;
        const __hip_bfloat16* s1 = xp1 + (size_t)fr*XFRM + (size_t)ohb*XROW;
        for (int u = threadIdx.x; u < 900; u += 256) {
            int par = u / 450;
            int rem = u - par*450;
            int rr  = rem / 45;
            int c   = rem - rr*45;           // 16B unit within row
            const __hip_bfloat16* s = (par ? s1 : s0) + rr*XROW + c*8;
            *(uint4*)&lx[par][rr][c*8] = *(const uint4*)s;
        }
    }
    __syncthreads();

    const s8v* wbp = (const s8v*)cwb;
    s8v bfrag[6];
    #pragma unroll
    for (int ks = 0; ks < 6; ++ks) bfrag[ks] = wbp[ks*64 + lane];

    const unsigned* lx32 = (const unsigned*)&lx[0][0][0];

    f4v acc[4];
    #pragma unroll
    for (int j = 0; j < 4; ++j) {
        int mm = lane & 15;
        int pp = p0 + j*4 + (mm >> 2);
        int pos = mm & 3;
        int pr = pp / 56, pc = pp - pr*56;
        int lr = 2*pr - ohb + (pos >> 1);    // 0..3
        int ow = 2*pc + (pos & 1);
        // dword base within lx: parity plane + row + elem offset (always even)
        const unsigned* xr = lx32 + ((ow & 1)*10 + lr)*184 + ((ow*3 + (ow & 1)) >> 1);

        f4v a4 = {0.f,0.f,0.f,0.f};
        #pragma unroll
        for (int ks = 0; ks < 6; ++ks) {
            int blk = ks*4 + quad;
            union { s8v v; unsigned u[4]; } av;
            av.v = (s8v){0,0,0,0,0,0,0,0};
            if (blk < 21) {
                int row = blk / 3;
                int off2 = (blk % 3) * 4;    // dwords
                const unsigned* p = xr + row*184 + off2;
                av.u[0] = p[0]; av.u[1] = p[1]; av.u[2] = p[2]; av.u[3] = p[3];
            }
            a4 = __builtin_amdgcn_mfma_f32_16x16x32_bf16(av.v, bfrag[ks], a4, 0,0,0);
        }
        acc[j] = a4;
    }

    // Epilogue: lane quad owns pooled px p0+j*4+quad, ch nlo; regs = 4 pos.
    int nlo = lane & 15;
    float bias_n = cb[nlo];
    #pragma unroll
    for (int j = 0; j < 4; ++j) {
        float* ap = (float*)&acc[j];
        float mx = fmaxf(fmaxf(ap[0], ap[1]), fmaxf(ap[2], ap[3]));
        float vv = fmaxf(mx + bias_n, 0.f);
        ((unsigned short*)pooled)[((size_t)fr*3136 + p0 + j*4 + quad)*16 + nlo] = f2bfu(vv);
    }
}

// Kernel 2a: zx via MFMA (R14, verified). One wave = 16 pt x 64 gates.
__global__ __launch_bounds__(256, 4) void zx_mfma_kernel(
    const __hip_bfloat16* __restrict__ pooled,  // [128][56][56][16] bf16
    const __hip_bfloat16* __restrict__ wkb,     // [4][5][64][8] bf16
    __hip_bfloat16* __restrict__ zx)            // [64][373248] bf16
{
    int wid  = (blockIdx.x << 2) + (threadIdx.x >> 6);  // 0..23327
    int lane = threadIdx.x & 63;
    int quad = lane >> 4;
    int pt0  = wid << 4;
    int m    = pt0 + (lane & 15);

    int b  = m / (TT*SPIX);
    int rt = m % (TT*SPIX);
    int tt = rt / SPIX;
    int r  = rt % SPIX;
    int oh = r / WO, ow = r % WO;
    const __hip_bfloat16* pf = pooled + (size_t)(b*TT + tt) * (HP*WP*16);

    f4v acc0 = {0.f,0.f,0.f,0.f}, acc1 = acc0, acc2 = acc0, acc3 = acc0;
    const s8v* wb = (const s8v*)wkb;

    #pragma unroll
    for (int ks = 0; ks < 5; ++ks) {
        int blk = ks*4 + quad;
        s8v a;
        if (blk < 18) {
            int tap = blk >> 1, half = blk & 1;
            int ky = tap / 3, kx = tap - ky*3;
            a = *(const s8v*)(pf + ((size_t)(oh+ky)*WP + (ow+kx))*16 + half*8);
        } else {
            a = (s8v){0,0,0,0,0,0,0,0};
        }
        acc0 = __builtin_amdgcn_mfma_f32_16x16x32_bf16(a, wb[(0*5+ks)*64 + lane], acc0, 0,0,0);
        acc1 = __builtin_amdgcn_mfma_f32_16x16x32_bf16(a, wb[(1*5+ks)*64 + lane], acc1, 0,0,0);
        acc2 = __builtin_amdgcn_mfma_f32_16x16x32_bf16(a, wb[(2*5+ks)*64 + lane], acc2, 0,0,0);
        acc3 = __builtin_amdgcn_mfma_f32_16x16x32_bf16(a, wb[(3*5+ks)*64 + lane], acc3, 0,0,0);
    }

    int nlo = lane & 15;
    size_t prow = (size_t)pt0 + quad*4;
    f4v accs[4] = {acc0, acc1, acc2, acc3};
    #pragma unroll
    for (int nt = 0; nt < 4; ++nt) {
        int n = nt*16 + nlo;
        uint2 u;
        u.x = pk2(accs[nt].x, accs[nt].y);
        u.y = pk2(accs[nt].z, accs[nt].w);
        *(uint2*)&zx[(size_t)n * NPT + prow] = u;
    }
}

// Kernel 2b (R28): one ConvLSTM step with LDS-staged h — the R2 conv cure
// applied to the scan. Model (fits R0/R6/R8/R4/R7): each wave-tile's serial
// chain costs ~10us (~24k cy) regardless of launch structure; boundaries are
// cheap. The chain = 18 scattered 16B h-tap global loads (same disease
// conv_mfma had pre-R2: all pipes idle, load serialization). Cure: block =
// (b, 2-row group), grid (27,8), 448 thr = 7 waves = 1 tile/wave. Stage h
// rows y0-1..y0+2 into LDS [4][56][16] (6.9KB, ring cols zero) with ONE
// coalesced uint4 load/thread (R7-verified staging pattern), then A-frags
// come from LDS (R8-phase-B-verified compute path; both ran absmax=0).
// zx/c loads share the same latency exposure before the barrier.
__global__ __launch_bounds__(448, 2) void lstm_step_mfma(
    const __hip_bfloat16* __restrict__ zx,   // [64][373248]
    const __hip_bfloat16* __restrict__ h_in, // [8,54,54,16] bf16
    __hip_bfloat16* __restrict__ h_out,
    float* __restrict__ cpl,                 // [16][23328] planar fp32
    const __hip_bfloat16* __restrict__ wrb,  // [4][5][64][8] bf16
    const float* __restrict__ bias,          // [64]
    int t)
{
    int g = blockIdx.x;                      // 0..26 (row pair, y0 = 2g)
    int b = blockIdx.y;                      // 0..7
    int y0 = 2*g;
    int tid  = threadIdx.x;
    int wv   = tid >> 6;                     // 0..6
    int lane = tid & 63;
    int quad = lane >> 4;
    int ml   = lane & 15;
    int ch   = ml;

    __shared__ __align__(16) short hbuf[4][56][16];   // 7,168 B = 448 uint4

    // Zero (1 uint4/thread exactly): ring cols + OOB rows = SAME-pad 0.
    ((uint4*)hbuf)[tid] = (uint4){0,0,0,0};

    const s8v* wbv = (const s8v*)wrb;
    s8v bfr[20];
    #pragma unroll
    for (int i = 0; i < 20; ++i) bfr[i] = wbv[i*64 + lane];

    float b_i = bias[ch], b_f = bias[16+ch], b_g = bias[32+ch], b_o = bias[48+ch];

    __syncthreads();                          // zeros visible

    // Stage h rows y0-1..y0+2 (coalesced: 432 uint4, 1/thread).
    {
        const unsigned short* hGin = (const unsigned short*)h_in;
        if (tid < 432) {
            int row = tid / 108;             // 0..3 -> global row y0-1+row
            int rem = tid - row*108;
            int px = rem >> 1, half = rem & 1;
            int ry = y0 - 1 + row;
            if ((ry >= 0) && (ry < HO)) {
                uint4 v = *(const uint4*)&hGin[((size_t)b*SPIX + (size_t)ry*54 + px)*16 + half*8];
                *(uint4*)&hbuf[row][px + 1][half*8] = v;
            }
        }
    }

    // zx / c loads: issued before the barrier so their latency overlaps
    // the staging exposure (barrier drains all vmcnt anyway).
    int rlo = y0*54, rhi = rlo + 108;        // rlo = 108g, multiple of 4
    int r0 = rlo + (wv << 4) + quad*4;
    size_t zb = (size_t)b*(TT*SPIX) + (size_t)t*SPIX;
    const unsigned short* zxp = (const unsigned short*)zx;
    ushort4 zi, zf, zg_, zo; float4 cold;
    if (r0 + 3 < rhi) {
        zi  = *(const ushort4*)&zxp[(size_t)( 0+ch)*NPT + zb + r0];
        zf  = *(const ushort4*)&zxp[(size_t)(16+ch)*NPT + zb + r0];
        zg_ = *(const ushort4*)&zxp[(size_t)(32+ch)*NPT + zb + r0];
        zo  = *(const ushort4*)&zxp[(size_t)(48+ch)*NPT + zb + r0];
        cold = *(const float4*)&cpl[(size_t)ch*NPIX + (size_t)b*SPIX + r0];
    } else {
        unsigned short* zv[4] = {(unsigned short*)&zi, (unsigned short*)&zf,
                                 (unsigned short*)&zg_, (unsigned short*)&zo};
        float* cv = (float*)&cold;
        #pragma unroll
        for (int e = 0; e < 4; ++e) {
            int re = r0 + e;
            bool ok = (re < rhi);
            #pragma unroll
            for (int gg = 0; gg < 4; ++gg)
                zv[gg][e] = ok ? zxp[(size_t)(gg*16+ch)*NPT + zb + re] : 0;
            cv[e] = ok ? cpl[(size_t)ch*NPIX + (size_t)b*SPIX + re] : 0.f;
        }
    }

    __syncthreads();                          // staging complete

    // A-fragments from LDS (R8 phase-B indexing, verified absmax 0).
    int rm  = rlo + (wv << 4) + ml;
    int yB  = rm / 54, xB = rm - yB*54;      // pad lanes: yB = y0+2
    int lrB = yB - y0;                       // 0..1 valid, 2 pad

    s8v afr[5];
    #pragma unroll
    for (int ks = 0; ks < 5; ++ks) {
        int blk = ks*4 + quad;
        s8v a = (s8v){0,0,0,0,0,0,0,0};
        if (blk < 18) {
            int tap = blk >> 1, half = blk & 1;
            int ky = tap / 3, kx = tap - ky*3;
            int row = lrB + ky;              // valid lanes: 0..3
            row = row > 3 ? 3 : row;         // pad lanes clamped in-bounds
            a = *(const s8v*)&hbuf[row][xB + kx][half*8];
        }
        afr[ks] = a;
    }

    f4v acc0 = {0.f,0.f,0.f,0.f}, acc1 = acc0, acc2 = acc0, acc3 = acc0;
    #pragma unroll
    for (int ks = 0; ks < 5; ++ks) {
        acc0 = __builtin_amdgcn_mfma_f32_16x16x32_bf16(afr[ks], bfr[0*5+ks], acc0, 0,0,0);
        acc1 = __builtin_amdgcn_mfma_f32_16x16x32_bf16(afr[ks], bfr[1*5+ks], acc1, 0,0,0);
        acc2 = __builtin_amdgcn_mfma_f32_16x16x32_bf16(afr[ks], bfr[2*5+ks], acc2, 0,0,0);
        acc3 = __builtin_amdgcn_mfma_f32_16x16x32_bf16(afr[ks], bfr[3*5+ks], acc3, 0,0,0);
    }

    // Epilogue: lane owns (px r0..r0+3, ch), guarded at region tail.
    const unsigned short* zip = (const unsigned short*)&zi;
    const unsigned short* zfp = (const unsigned short*)&zf;
    const unsigned short* zgp = (const unsigned short*)&zg_;
    const unsigned short* zop = (const unsigned short*)&zo;
    float* a0 = (float*)&acc0; float* a1 = (float*)&acc1;
    float* a2 = (float*)&acc2; float* a3 = (float*)&acc3;
    float* co = (float*)&cold;
    #pragma unroll
    for (int reg = 0; reg < 4; ++reg) {
        int rr = r0 + reg;
        if (rr < rhi) {
            float iv = hsig (a0[reg] + bf2f(zip[reg]) + b_i);
            float fv = hsig (a1[reg] + bf2f(zfp[reg]) + b_f);
            float gv = tanhf(a2[reg] + bf2f(zgp[reg]) + b_g);
            float ov = hsig (a3[reg] + bf2f(zop[reg]) + b_o);
            float cc = fv * co[reg] + iv * gv;
            float hv = ov * tanhf(cc);
            cpl[(size_t)ch*NPIX + (size_t)b*SPIX + rr] = cc;
            ((unsigned short*)h_out)[((size_t)b*SPIX + rr)*16 + ch] = f2bfu(hv);
        }
    }
}

// Kernel 3: spatial mean (bf16 h) -> dense(16->6) -> softmax. One block per b.
// R18: short8 loads, 1024 threads, parity-preserving LDS tree (verified win).
__global__ __launch_bounds__(1024) void head_kernel(
    const __hip_bfloat16* __restrict__ h,   // [8,54,54,16] bf16
    const float* __restrict__ dw,   // [16,6]
    const float* __restrict__ db,   // [6]
    float* __restrict__ out)        // [8,6]
{
    int b = blockIdx.x;
    int tid = threadIdx.x;
    const s8v* hb = (const s8v*)(h + (size_t)b * SPIX * 16);  // 5832 s8v per b

    float acc[8] = {0.f,0.f,0.f,0.f,0.f,0.f,0.f,0.f};
    for (int j = tid; j < SPIX*2; j += 1024) {
        s8v v = hb[j];
        #pragma unroll
        for (int k = 0; k < 8; ++k) acc[k] += bf2f((unsigned short)v[k]);
    }

    __shared__ float red[1024][8];           // 32 KB
    #pragma unroll
    for (int k = 0; k < 8; ++k) red[tid][k] = acc[k];
    __syncthreads();
    for (int st = 512; st >= 2; st >>= 1) {
        if (tid < st) {
            #pragma unroll
            for (int k = 0; k < 8; ++k) red[tid][k] += red[tid + st][k];
        }
        __syncthreads();
    }

    __shared__ float logits[8];
    if (tid < NC) {
        float l = db[tid];
        #pragma unroll
        for (int k = 0; k < 8; ++k) {
            l += (red[0][k] * (1.0f/2916.0f)) * dw[k*NC + tid];
            l += (red[1][k] * (1.0f/2916.0f)) * dw[(8+k)*NC + tid];
        }
        logits[tid] = l;
    }
    __syncthreads();
    if (tid < NC) {
        float m = -1e30f;
        for (int k = 0; k < NC; ++k) m = fmaxf(m, logits[k]);
        float e = expf(logits[tid] - m);
        float d = 0.0f;
        for (int k = 0; k < NC; ++k) d += expf(logits[k] - m);
        out[b*NC + tid] = e / d;
    }
}

extern "C" void kernel_launch(void* const* d_in, const int* in_sizes, int n_in,
                              void* d_out, int out_size, void* d_ws, size_t ws_size,
                              hipStream_t stream) {
    const float* x      = (const float*)d_in[0];
    const float* conv_w = (const float*)d_in[1];
    const float* conv_b = (const float*)d_in[2];
    const float* wk     = (const float*)d_in[3];
    const float* wr     = (const float*)d_in[4];
    const float* bias   = (const float*)d_in[5];
    const float* dw     = (const float*)d_in[6];
    const float* db     = (const float*)d_in[7];
    float* out = (float*)d_out;

    char* base = (char*)d_ws;
    __hip_bfloat16* pooled = (__hip_bfloat16*)base;                 // 12.85 MB
    __hip_bfloat16* hA  = pooled + POOLED_BF16;                     // 746 KB
    __hip_bfloat16* hB  = hA + NPIX*16;
    __hip_bfloat16* wkb = hB + NPIX*16;                             // 20 KB
    __hip_bfloat16* wrb = wkb + 10240;                              // 20 KB
    __hip_bfloat16* cwb = wrb + 10240;                              // 6 KB
    float* cpl = (float*)(cwb + 3072);                              // 1.49 MB
    __hip_bfloat16* zx  = (__hip_bfloat16*)(cpl + NPIX*16);         // 47.8 MB
    // xpad parity copies ALIAS zx (consumed before zx is written).
    __hip_bfloat16* xp0 = zx;
    __hip_bfloat16* xp1 = zx + XPAD_ELEMS;

    // One prep dispatch: xpad + wk/wr/cw prepack + c0/h0 zero.
    prep_kernel<<<dim3(5950), dim3(256), 0, stream>>>(
        x, xp0, xp1, wk, wkb, wr, wrb, conv_w, cwb, cpl, hA);
    conv_mfma_kernel<<<dim3(49, 128), dim3(256), 0, stream>>>(xp0, xp1, cwb, conv_b, pooled);
    zx_mfma_kernel<<<dim3(5832), dim3(256), 0, stream>>>(pooled, wkb, zx);

    for (int t = 0; t < TT; ++t) {
        const __hip_bfloat16* hin  = (t & 1) ? hB : hA;
        __hip_bfloat16*       hout = (t & 1) ? hA : hB;
        lstm_step_mfma<<<dim3(27, 8), dim3(448), 0, stream>>>(
            zx, hin, hout, cpl, wrb, bias, t);
    }
    // t=15 (odd) wrote hA
    head_kernel<<<dim3(8), dim3(1024), 0, stream>>>(hA, dw, db, out);
}

// Round 12
// 242.629 us; speedup vs baseline: 5.2658x; 1.0227x over previous
//
#include <hip/hip_runtime.h>
#include <hip/hip_bf16.h>
#include <math.h>

// Problem dims
#define BB 8
#define TT 16
#define HH 112
#define WW 112
#define CC 3
#define FF 16
#define HP 56
#define WP 56
#define HO 54
#define WO 54
#define NC 6

#define NPIX (BB*HO*WO)               // 23328
#define SPIX (HO*WO)                  // 2916
#define NPT  (BB*TT*SPIX)             // 373248  (b,t,pixel)
#define POOLED_BF16  (128*56*56*16)   // 6,422,528 bf16

// xpad: per-frame bf16 rows with halo + pad: 118 rows x 360 elems
#define XROW 360
#define XFRM (118*XROW)               // 42,480
#define XPAD_ELEMS (128*XFRM)         // 5,437,440 per parity copy

typedef __attribute__((ext_vector_type(8))) short s8v;   // 8 bf16 (4 VGPRs)
typedef __attribute__((ext_vector_type(4))) float f4v;   // MFMA acc

__device__ __forceinline__ float hsig(float x) {
    return fminf(fmaxf(0.2f*x + 0.5f, 0.0f), 1.0f);
}
__device__ __forceinline__ unsigned pk2(float lo, float hi) {
    union { __hip_bfloat16 h; unsigned short u; } a, b;
    a.h = __float2bfloat16(lo); b.h = __float2bfloat16(hi);
    return ((unsigned)b.u << 16) | (unsigned)a.u;
}
__device__ __forceinline__ float bf2f(unsigned short u) {
    union { unsigned v; float f; } x; x.v = ((unsigned)u) << 16; return x.f;
}
__device__ __forceinline__ unsigned short f2bfu(float f) {
    union { __hip_bfloat16 h; unsigned short u; } v;
    v.h = __float2bfloat16(f); return v.u;
}

// ---------- prep job bodies (verbatim logic, virtual block id) ----------
__device__ __forceinline__ void w_prepack_body(int vb, const float* __restrict__ w,
                                               __hip_bfloat16* __restrict__ wb)
{
    int i = vb * 256 + threadIdx.x;                // 40*256 = 10240 exact
    int j    = i & 7;
    int lane = (i >> 3) & 63;
    int ks   = (i >> 9) % 5;
    int nt   = (i >> 9) / 5;
    int k = ks*32 + ((lane >> 4) & 3)*8 + j;
    int n = nt*16 + (lane & 15);
    float v = 0.f;
    if (k < 144) {
        int tap = k >> 4, ci = k & 15;
        v = w[tap*1024 + ci*64 + n];
    }
    wb[i] = __float2bfloat16(v);
}

__device__ __forceinline__ void cw_prepack_body(int vb, const float* __restrict__ cw,
                                                __hip_bfloat16* __restrict__ cwb)
{
    int i = vb * 256 + threadIdx.x;                // 12*256 = 3072 exact
    int j    = i & 7;
    int lane = (i >> 3) & 63;
    int ks   = i >> 9;                             // 0..5
    int k = ks*32 + ((lane >> 4) & 3)*8 + j;
    int n = lane & 15;
    float v = 0.f;
    if (k < 168) {
        int row = k / 24, idx = k % 24;
        if (idx < 21) {
            int kx = idx / 3, ci = idx % 3;
            v = cw[((row*7 + kx)*3 + ci)*16 + n];
        }
    }
    cwb[i] = __float2bfloat16(v);
}

__device__ __forceinline__ void xpad_body(int vb, const float* __restrict__ x,
                                          __hip_bfloat16* __restrict__ xp0,
                                          __hip_bfloat16* __restrict__ xp1)
{
    int idx = vb * 256 + threadIdx.x;              // 5310*256 = 1,359,360 exact
    int e4 = idx % 90;
    int rr = (idx / 90) % 118;
    int fr = idx / (90*118);
    int e0 = e4 * 4;
    int ir = rr - 3;
    const float* xf = x + (size_t)fr * (112*336);
    bool rowok = (ir >= 0) & (ir < 112);

    float v[5];
    #pragma unroll
    for (int i = 0; i < 5; ++i) {
        int s = e0 - 1 + i;
        bool ok = rowok & (s >= 9) & (s < 345);
        v[i] = ok ? xf[ir*336 + (s - 9)] : 0.f;
    }
    size_t o = ((size_t)fr*118 + rr) * XROW + e0;
    uint2 a0, a1;
    a0.x = pk2(v[1], v[2]); a0.y = pk2(v[3], v[4]);
    a1.x = pk2(v[0], v[1]); a1.y = pk2(v[2], v[3]);
    *(uint2*)&xp0[o] = a0;
    *(uint2*)&xp1[o] = a1;
}

// Kernel 0 (R26, kept): ALL independent prep work in ONE dispatch.
__global__ __launch_bounds__(256) void prep_kernel(
    const float* __restrict__ x,
    __hip_bfloat16* __restrict__ xp0, __hip_bfloat16* __restrict__ xp1,
    const float* __restrict__ wk, __hip_bfloat16* __restrict__ wkb,
    const float* __restrict__ wr, __hip_bfloat16* __restrict__ wrb,
    const float* __restrict__ cw, __hip_bfloat16* __restrict__ cwb,
    float* __restrict__ cpl, __hip_bfloat16* __restrict__ hA)
{
    int bid = blockIdx.x;
    if (bid < 5310) { xpad_body(bid, x, xp0, xp1); return; }
    bid -= 5310;
    if (bid < 40) { w_prepack_body(bid, wk, wkb); return; }
    bid -= 40;
    if (bid < 40) { w_prepack_body(bid, wr, wrb); return; }
    bid -= 40;
    if (bid < 12) { cw_prepack_body(bid, cw, cwb); return; }
    bid -= 12;
    if (bid < 365) {                               // c0 = 0
        int u = bid*256 + threadIdx.x;
        if (u < 93312) ((uint4*)cpl)[u] = (uint4){0,0,0,0};
        return;
    }
    bid -= 365;
    {                                              // h0 = 0
        int u = bid*256 + threadIdx.x;
        if (u < 46656) ((uint4*)hA)[u] = (uint4){0,0,0,0};
    }
}

// Kernel 1: conv 7x7 + bias + relu + maxpool via MFMA.
// R20: LDS-staged input rows (verified win: 47.6 -> ~15 us).
__global__ __launch_bounds__(256, 6) void conv_mfma_kernel(
    const __hip_bfloat16* __restrict__ xp0,
    const __hip_bfloat16* __restrict__ xp1,
    const __hip_bfloat16* __restrict__ cwb,  // [6][64][8]
    const float* __restrict__ cb,            // [16]
    __hip_bfloat16* __restrict__ pooled)     // [128,56,56,16] bf16
{
    int wv = threadIdx.x >> 6;
    int lane = threadIdx.x & 63;
    int quad = lane >> 4;
    int fr = blockIdx.y;
    int p0b = blockIdx.x * 64;               // block's pooled px base
    int p0 = p0b + wv * 16;                  // wave's pooled px base

    __shared__ short lx[2][10][368];         // 14,720 B
    int pr0 = p0b / 56;
    int ohb = 2 * pr0;                       // first staged input row
    {
        const __hip_bfloat16* s0 = xp0 + (size_t)fr*XFRM + (size_t)ohb*XROW;
        const __hip_bfloat16* s1 = xp1 + (size_t)fr*XFRM + (size_t)ohb*XROW;
        for (int u = threadIdx.x; u < 900; u += 256) {
            int par = u / 450;
            int rem = u - par*450;
            int rr  = rem / 45;
            int c   = rem - rr*45;           // 16B unit within row
            const __hip_bfloat16* s = (par ? s1 : s0) + rr*XROW + c*8;
            *(uint4*)&lx[par][rr][c*8] = *(const uint4*)s;
        }
    }
    __syncthreads();

    const s8v* wbp = (const s8v*)cwb;
    s8v bfrag[6];
    #pragma unroll
    for (int ks = 0; ks < 6; ++ks) bfrag[ks] = wbp[ks*64 + lane];

    const unsigned* lx32 = (const unsigned*)&lx[0][0][0];

    f4v acc[4];
    #pragma unroll
    for (int j = 0; j < 4; ++j) {
        int mm = lane & 15;
        int pp = p0 + j*4 + (mm >> 2);
        int pos = mm & 3;
        int pr = pp / 56, pc = pp - pr*56;
        int lr = 2*pr - ohb + (pos >> 1);    // 0..3
        int ow = 2*pc + (pos & 1);
        const unsigned* xr = lx32 + ((ow & 1)*10 + lr)*184 + ((ow*3 + (ow & 1)) >> 1);

        f4v a4 = {0.f,0.f,0.f,0.f};
        #pragma unroll
        for (int ks = 0; ks < 6; ++ks) {
            int blk = ks*4 + quad;
            union { s8v v; unsigned u[4]; } av;
            av.v = (s8v){0,0,0,0,0,0,0,0};
            if (blk < 21) {
                int row = blk / 3;
                int off2 = (blk % 3) * 4;    // dwords
                const unsigned* p = xr + row*184 + off2;
                av.u[0] = p[0]; av.u[1] = p[1]; av.u[2] = p[2]; av.u[3] = p[3];
            }
            a4 = __builtin_amdgcn_mfma_f32_16x16x32_bf16(av.v, bfrag[ks], a4, 0,0,0);
        }
        acc[j] = a4;
    }

    int nlo = lane & 15;
    float bias_n = cb[nlo];
    #pragma unroll
    for (int j = 0; j < 4; ++j) {
        float* ap = (float*)&acc[j];
        float mx = fmaxf(fmaxf(ap[0], ap[1]), fmaxf(ap[2], ap[3]));
        float vv = fmaxf(mx + bias_n, 0.f);
        ((unsigned short*)pooled)[((size_t)fr*3136 + p0 + j*4 + quad)*16 + nlo] = f2bfu(vv);
    }
}

// Kernel 2a: zx via MFMA (R14, verified). One wave = 16 pt x 64 gates.
__global__ __launch_bounds__(256, 4) void zx_mfma_kernel(
    const __hip_bfloat16* __restrict__ pooled,  // [128][56][56][16] bf16
    const __hip_bfloat16* __restrict__ wkb,     // [4][5][64][8] bf16
    __hip_bfloat16* __restrict__ zx)            // [64][373248] bf16
{
    int wid  = (blockIdx.x << 2) + (threadIdx.x >> 6);  // 0..23327
    int lane = threadIdx.x & 63;
    int quad = lane >> 4;
    int pt0  = wid << 4;
    int m    = pt0 + (lane & 15);

    int b  = m / (TT*SPIX);
    int rt = m % (TT*SPIX);
    int tt = rt / SPIX;
    int r  = rt % SPIX;
    int oh = r / WO, ow = r % WO;
    const __hip_bfloat16* pf = pooled + (size_t)(b*TT + tt) * (HP*WP*16);

    f4v acc0 = {0.f,0.f,0.f,0.f}, acc1 = acc0, acc2 = acc0, acc3 = acc0;
    const s8v* wb = (const s8v*)wkb;

    #pragma unroll
    for (int ks = 0; ks < 5; ++ks) {
        int blk = ks*4 + quad;
        s8v a;
        if (blk < 18) {
            int tap = blk >> 1, half = blk & 1;
            int ky = tap / 3, kx = tap - ky*3;
            a = *(const s8v*)(pf + ((size_t)(oh+ky)*WP + (ow+kx))*16 + half*8);
        } else {
            a = (s8v){0,0,0,0,0,0,0,0};
        }
        acc0 = __builtin_amdgcn_mfma_f32_16x16x32_bf16(a, wb[(0*5+ks)*64 + lane], acc0, 0,0,0);
        acc1 = __builtin_amdgcn_mfma_f32_16x16x32_bf16(a, wb[(1*5+ks)*64 + lane], acc1, 0,0,0);
        acc2 = __builtin_amdgcn_mfma_f32_16x16x32_bf16(a, wb[(2*5+ks)*64 + lane], acc2, 0,0,0);
        acc3 = __builtin_amdgcn_mfma_f32_16x16x32_bf16(a, wb[(3*5+ks)*64 + lane], acc3, 0,0,0);
    }

    int nlo = lane & 15;
    size_t prow = (size_t)pt0 + quad*4;
    f4v accs[4] = {acc0, acc1, acc2, acc3};
    #pragma unroll
    for (int nt = 0; nt < 4; ++nt) {
        int n = nt*16 + nlo;
        uint2 u;
        u.x = pk2(accs[nt].x, accs[nt].y);
        u.y = pk2(accs[nt].z, accs[nt].w);
        *(uint2*)&zx[(size_t)n * NPT + prow] = u;
    }
}

// Kernel 2b (R29): gate-split ConvLSTM step = R1's wave decomposition with
// its three poisons removed. Accounting: boundary ~2us (R9 prep-merge), so
// each step EXECUTES ~10.5us with all pipes idle. Remaining chain suspects,
// all removed here: (1) 20 serialized B-frag loads/wave (compiler never
// keeps them resident: R7 showed VGPR_Count=84 < the 164 needed) -> now 5
// per wave (gate-split); (2) 5.7 waves/CU TLP -> now 23 (5888 waves);
// (3) scattered/scalar gate gathers -> epilogue is 1 thread per (px,ch)
// with fully coalesced zx/c (128B per wave per gate) and h-out transposed
// through LDS into one contiguous 2KB store.
// Block = 64 px of one b: grid (46,8), 1024 thr = 4 px-tiles x 4 gate-waves.
// h staged in LDS (R10-verified): rows yf-1..yf+3, ring cols.
__global__ __launch_bounds__(1024, 1) void lstm_step_mfma(
    const __hip_bfloat16* __restrict__ zx,   // [64][373248]
    const __hip_bfloat16* __restrict__ h_in, // [8,54,54,16] bf16
    __hip_bfloat16* __restrict__ h_out,
    float* __restrict__ cpl,                 // [16][23328] planar fp32
    const __hip_bfloat16* __restrict__ wrb,  // [4][5][64][8] bf16
    const float* __restrict__ bias,          // [64]
    int t)
{
    int reg6 = blockIdx.x;                   // 0..45 (64-px region)
    int b    = blockIdx.y;                   // 0..7
    int r0   = reg6 * 64;                    // region base px
    int npx  = SPIX - r0; if (npx > 64) npx = 64;   // 64, last region 36
    int tid  = threadIdx.x;
    int wv   = tid >> 6;                     // 0..15
    int lane = tid & 63;
    int quad = lane >> 4;
    int ml   = lane & 15;
    int tile = wv >> 2;                      // 0..3 (16-px tile)
    int gate = wv & 3;                       // 0..3 (i,f,g,o)

    __shared__ __align__(16) short hbuf[5][56][16];      // 8,960 B
    __shared__ float zacc[4][4][16][17];                 // 17,408 B (padded)
    __shared__ short hstage[64][18];                     // 2,304 B (padded)

    // Zero hbuf (560 uint4) - ring cols + OOB rows = SAME-pad 0.
    if (tid < 560) ((uint4*)hbuf)[tid] = (uint4){0,0,0,0};

    // This wave's 5 B-fragments (one gate block).
    const s8v* wbv = (const s8v*)wrb;
    s8v bfr[5];
    #pragma unroll
    for (int ks = 0; ks < 5; ++ks) bfr[ks] = wbv[(gate*5 + ks)*64 + lane];

    int yf = r0 / 54;                        // first row of region
    __syncthreads();                          // zeros visible

    // Stage h rows yf-1..yf+3 (540 uint4, coalesced, 1/thread).
    if (tid < 540) {
        int row = tid / 108;                 // 0..4 -> global row yf-1+row
        int rem = tid - row*108;
        int px = rem >> 1, half = rem & 1;
        int ry = yf - 1 + row;
        if ((ry >= 0) && (ry < HO)) {
            uint4 v = *(const uint4*)((const unsigned short*)h_in
                        + ((size_t)b*SPIX + (size_t)ry*54 + px)*16 + half*8);
            *(uint4*)&hbuf[row][px + 1][half*8] = v;
        }
    }
    __syncthreads();                          // staging complete

    // A-fragments from LDS; MFMA for (tile, gate).
    {
        int rl = tile*16 + ml;               // px within region (M row)
        if (rl >= npx) rl = 0;               // pad lanes: clamped, discarded
        int rm = r0 + rl;
        int y  = rm / 54, x = rm - y*54;
        int d  = y - yf;                     // 0..2

        s8v afr[5];
        #pragma unroll
        for (int ks = 0; ks < 5; ++ks) {
            int blk = ks*4 + quad;
            s8v a = (s8v){0,0,0,0,0,0,0,0};
            if (blk < 18) {
                int tap = blk >> 1, half = blk & 1;
                int ky = tap / 3, kx = tap - ky*3;
                a = *(const s8v*)&hbuf[d + ky][x + kx][half*8];
            }
            afr[ks] = a;
        }

        f4v acc = {0.f,0.f,0.f,0.f};
        #pragma unroll
        for (int ks = 0; ks < 5; ++ks)
            acc = __builtin_amdgcn_mfma_f32_16x16x32_bf16(afr[ks], bfr[ks], acc, 0,0,0);

        // zacc[tile][gate][px16][ch]: reg r -> px16 = quad*4+r, ch = ml.
        float* ap = (float*)&acc;
        #pragma unroll
        for (int r = 0; r < 4; ++r)
            zacc[tile][gate][quad*4 + r][ml] = ap[r];
    }
    __syncthreads();

    // Epilogue: thread = (ch, pxl). Coalesced zx/c; h via LDS transpose.
    {
        int ch  = tid >> 6;                  // 0..15
        int pxl = tid & 63;                  // 0..63
        bool ok = (pxl < npx);
        int tl  = pxl >> 4, p16 = pxl & 15;
        size_t ptz = (size_t)b*(TT*SPIX) + (size_t)t*SPIX + r0 + pxl;
        const unsigned short* zxp = (const unsigned short*)zx;

        float zi = 0.f, zf = 0.f, zg = 0.f, zo = 0.f, cold = 0.f;
        if (ok) {
            zi = zacc[tl][0][p16][ch] + bf2f(zxp[(size_t)( 0+ch)*NPT + ptz]);
            zf = zacc[tl][1][p16][ch] + bf2f(zxp[(size_t)(16+ch)*NPT + ptz]);
            zg = zacc[tl][2][p16][ch] + bf2f(zxp[(size_t)(32+ch)*NPT + ptz]);
            zo = zacc[tl][3][p16][ch] + bf2f(zxp[(size_t)(48+ch)*NPT + ptz]);
            cold = cpl[(size_t)ch*NPIX + (size_t)b*SPIX + r0 + pxl];
        }
        float iv = hsig(zi + bias[ch]);
        float fv = hsig(zf + bias[16+ch]);
        float gv = tanhf(zg + bias[32+ch]);
        float ov = hsig(zo + bias[48+ch]);
        float cc = fv * cold + iv * gv;
        float hv = ov * tanhf(cc);
        if (ok) {
            cpl[(size_t)ch*NPIX + (size_t)b*SPIX + r0 + pxl] = cc;
            hstage[pxl][ch] = (short)f2bfu(hv);
        }
    }
    __syncthreads();

    // Transposed h write: thread = (px, ch) -> contiguous 2KB per block.
    {
        int px = tid >> 4, ch = tid & 15;
        if (px < npx)
            ((unsigned short*)h_out)[((size_t)b*SPIX + r0 + px)*16 + ch] =
                (unsigned short)hstage[px][ch];
    }
}

// Kernel 3: spatial mean (bf16 h) -> dense(16->6) -> softmax. One block per b.
// R18: short8 loads, 1024 threads, parity-preserving LDS tree (verified win).
__global__ __launch_bounds__(1024) void head_kernel(
    const __hip_bfloat16* __restrict__ h,   // [8,54,54,16] bf16
    const float* __restrict__ dw,   // [16,6]
    const float* __restrict__ db,   // [6]
    float* __restrict__ out)        // [8,6]
{
    int b = blockIdx.x;
    int tid = threadIdx.x;
    const s8v* hb = (const s8v*)(h + (size_t)b * SPIX * 16);  // 5832 s8v per b

    float acc[8] = {0.f,0.f,0.f,0.f,0.f,0.f,0.f,0.f};
    for (int j = tid; j < SPIX*2; j += 1024) {
        s8v v = hb[j];
        #pragma unroll
        for (int k = 0; k < 8; ++k) acc[k] += bf2f((unsigned short)v[k]);
    }

    __shared__ float red[1024][8];           // 32 KB
    #pragma unroll
    for (int k = 0; k < 8; ++k) red[tid][k] = acc[k];
    __syncthreads();
    for (int st = 512; st >= 2; st >>= 1) {
        if (tid < st) {
            #pragma unroll
            for (int k = 0; k < 8; ++k) red[tid][k] += red[tid + st][k];
        }
        __syncthreads();
    }

    __shared__ float logits[8];
    if (tid < NC) {
        float l = db[tid];
        #pragma unroll
        for (int k = 0; k < 8; ++k) {
            l += (red[0][k] * (1.0f/2916.0f)) * dw[k*NC + tid];
            l += (red[1][k] * (1.0f/2916.0f)) * dw[(8+k)*NC + tid];
        }
        logits[tid] = l;
    }
    __syncthreads();
    if (tid < NC) {
        float m = -1e30f;
        for (int k = 0; k < NC; ++k) m = fmaxf(m, logits[k]);
        float e = expf(logits[tid] - m);
        float d = 0.0f;
        for (int k = 0; k < NC; ++k) d += expf(logits[k] - m);
        out[b*NC + tid] = e / d;
    }
}

extern "C" void kernel_launch(void* const* d_in, const int* in_sizes, int n_in,
                              void* d_out, int out_size, void* d_ws, size_t ws_size,
                              hipStream_t stream) {
    const float* x      = (const float*)d_in[0];
    const float* conv_w = (const float*)d_in[1];
    const float* conv_b = (const float*)d_in[2];
    const float* wk     = (const float*)d_in[3];
    const float* wr     = (const float*)d_in[4];
    const float* bias   = (const float*)d_in[5];
    const float* dw     = (const float*)d_in[6];
    const float* db     = (const float*)d_in[7];
    float* out = (float*)d_out;

    char* base = (char*)d_ws;
    __hip_bfloat16* pooled = (__hip_bfloat16*)base;                 // 12.85 MB
    __hip_bfloat16* hA  = pooled + POOLED_BF16;                     // 746 KB
    __hip_bfloat16* hB  = hA + NPIX*16;
    __hip_bfloat16* wkb = hB + NPIX*16;                             // 20 KB
    __hip_bfloat16* wrb = wkb + 10240;                              // 20 KB
    __hip_bfloat16* cwb = wrb + 10240;                              // 6 KB
    float* cpl = (float*)(cwb + 3072);                              // 1.49 MB
    __hip_bfloat16* zx  = (__hip_bfloat16*)(cpl + NPIX*16);         // 47.8 MB
    // xpad parity copies ALIAS zx (consumed before zx is written).
    __hip_bfloat16* xp0 = zx;
    __hip_bfloat16* xp1 = zx + XPAD_ELEMS;

    // One prep dispatch: xpad + wk/wr/cw prepack + c0/h0 zero.
    prep_kernel<<<dim3(5950), dim3(256), 0, stream>>>(
        x, xp0, xp1, wk, wkb, wr, wrb, conv_w, cwb, cpl, hA);
    conv_mfma_kernel<<<dim3(49, 128), dim3(256), 0, stream>>>(xp0, xp1, cwb, conv_b, pooled);
    zx_mfma_kernel<<<dim3(5832), dim3(256), 0, stream>>>(pooled, wkb, zx);

    for (int t = 0; t < TT; ++t) {
        const __hip_bfloat16* hin  = (t & 1) ? hB : hA;
        __hip_bfloat16*       hout = (t & 1) ? hA : hB;
        lstm_step_mfma<<<dim3(46, 8), dim3(1024), 0, stream>>>(
            zx, hin, hout, cpl, wrb, bias, t);
    }
    // t=15 (odd) wrote hA
    head_kernel<<<dim3(8), dim3(1024), 0, stream>>>(hA, dw, db, out);
}

// Round 13
// 237.645 us; speedup vs baseline: 5.3763x; 1.0210x over previous
//
#include <hip/hip_runtime.h>
#include <hip/hip_bf16.h>
#include <math.h>

// Problem dims
#define BB 8
#define TT 16
#define HH 112
#define WW 112
#define CC 3
#define FF 16
#define HP 56
#define WP 56
#define HO 54
#define WO 54
#define NC 6

#define NPIX (BB*HO*WO)               // 23328
#define SPIX (HO*WO)                  // 2916
#define NPT  (BB*TT*SPIX)             // 373248  (b,t,pixel)
#define POOLED_BF16  (128*56*56*16)   // 6,422,528 bf16

// xpad: per-frame bf16 rows with halo + pad: 118 rows x 360 elems
#define XROW 360
#define XFRM (118*XROW)               // 42,480
#define XPAD_ELEMS (128*XFRM)         // 5,437,440 per parity copy

typedef __attribute__((ext_vector_type(8))) short s8v;   // 8 bf16 (4 VGPRs)
typedef __attribute__((ext_vector_type(4))) float f4v;   // MFMA acc

__device__ __forceinline__ float hsig(float x) {
    return fminf(fmaxf(0.2f*x + 0.5f, 0.0f), 1.0f);
}
__device__ __forceinline__ unsigned pk2(float lo, float hi) {
    union { __hip_bfloat16 h; unsigned short u; } a, b;
    a.h = __float2bfloat16(lo); b.h = __float2bfloat16(hi);
    return ((unsigned)b.u << 16) | (unsigned)a.u;
}
__device__ __forceinline__ float bf2f(unsigned short u) {
    union { unsigned v; float f; } x; x.v = ((unsigned)u) << 16; return x.f;
}
__device__ __forceinline__ unsigned short f2bfu(float f) {
    union { __hip_bfloat16 h; unsigned short u; } v;
    v.h = __float2bfloat16(f); return v.u;
}

// ---------- prep job bodies (verbatim logic, virtual block id) ----------
__device__ __forceinline__ void w_prepack_body(int vb, const float* __restrict__ w,
                                               __hip_bfloat16* __restrict__ wb)
{
    int i = vb * 256 + threadIdx.x;                // 40*256 = 10240 exact
    int j    = i & 7;
    int lane = (i >> 3) & 63;
    int ks   = (i >> 9) % 5;
    int nt   = (i >> 9) / 5;
    int k = ks*32 + ((lane >> 4) & 3)*8 + j;
    int n = nt*16 + (lane & 15);
    float v = 0.f;
    if (k < 144) {
        int tap = k >> 4, ci = k & 15;
        v = w[tap*1024 + ci*64 + n];
    }
    wb[i] = __float2bfloat16(v);
}

__device__ __forceinline__ void cw_prepack_body(int vb, const float* __restrict__ cw,
                                                __hip_bfloat16* __restrict__ cwb)
{
    int i = vb * 256 + threadIdx.x;                // 12*256 = 3072 exact
    int j    = i & 7;
    int lane = (i >> 3) & 63;
    int ks   = i >> 9;                             // 0..5
    int k = ks*32 + ((lane >> 4) & 3)*8 + j;
    int n = lane & 15;
    float v = 0.f;
    if (k < 168) {
        int row = k / 24, idx = k % 24;
        if (idx < 21) {
            int kx = idx / 3, ci = idx % 3;
            v = cw[((row*7 + kx)*3 + ci)*16 + n];
        }
    }
    cwb[i] = __float2bfloat16(v);
}

__device__ __forceinline__ void xpad_body(int vb, const float* __restrict__ x,
                                          __hip_bfloat16* __restrict__ xp0,
                                          __hip_bfloat16* __restrict__ xp1)
{
    int idx = vb * 256 + threadIdx.x;              // 5310*256 = 1,359,360 exact
    int e4 = idx % 90;
    int rr = (idx / 90) % 118;
    int fr = idx / (90*118);
    int e0 = e4 * 4;
    int ir = rr - 3;
    const float* xf = x + (size_t)fr * (112*336);
    bool rowok = (ir >= 0) & (ir < 112);

    float v[5];
    #pragma unroll
    for (int i = 0; i < 5; ++i) {
        int s = e0 - 1 + i;
        bool ok = rowok & (s >= 9) & (s < 345);
        v[i] = ok ? xf[ir*336 + (s - 9)] : 0.f;
    }
    size_t o = ((size_t)fr*118 + rr) * XROW + e0;
    uint2 a0, a1;
    a0.x = pk2(v[1], v[2]); a0.y = pk2(v[3], v[4]);
    a1.x = pk2(v[0], v[1]); a1.y = pk2(v[2], v[3]);
    *(uint2*)&xp0[o] = a0;
    *(uint2*)&xp1[o] = a1;
}

// Kernel 0 (R26, kept): ALL independent prep work in ONE dispatch.
__global__ __launch_bounds__(256) void prep_kernel(
    const float* __restrict__ x,
    __hip_bfloat16* __restrict__ xp0, __hip_bfloat16* __restrict__ xp1,
    const float* __restrict__ wk, __hip_bfloat16* __restrict__ wkb,
    const float* __restrict__ wr, __hip_bfloat16* __restrict__ wrb,
    const float* __restrict__ cw, __hip_bfloat16* __restrict__ cwb,
    float* __restrict__ cpl, __hip_bfloat16* __restrict__ hA)
{
    int bid = blockIdx.x;
    if (bid < 5310) { xpad_body(bid, x, xp0, xp1); return; }
    bid -= 5310;
    if (bid < 40) { w_prepack_body(bid, wk, wkb); return; }
    bid -= 40;
    if (bid < 40) { w_prepack_body(bid, wr, wrb); return; }
    bid -= 40;
    if (bid < 12) { cw_prepack_body(bid, cw, cwb); return; }
    bid -= 12;
    if (bid < 365) {                               // c0 = 0
        int u = bid*256 + threadIdx.x;
        if (u < 93312) ((uint4*)cpl)[u] = (uint4){0,0,0,0};
        return;
    }
    bid -= 365;
    {                                              // h0 = 0
        int u = bid*256 + threadIdx.x;
        if (u < 46656) ((uint4*)hA)[u] = (uint4){0,0,0,0};
    }
}

// Kernel 1: conv 7x7 + bias + relu + maxpool via MFMA.
// R20: LDS-staged input rows (verified win: 47.6 -> ~15 us).
__global__ __launch_bounds__(256, 6) void conv_mfma_kernel(
    const __hip_bfloat16* __restrict__ xp0,
    const __hip_bfloat16* __restrict__ xp1,
    const __hip_bfloat16* __restrict__ cwb,  // [6][64][8]
    const float* __restrict__ cb,            // [16]
    __hip_bfloat16* __restrict__ pooled)     // [128,56,56,16] bf16
{
    int wv = threadIdx.x >> 6;
    int lane = threadIdx.x & 63;
    int quad = lane >> 4;
    int fr = blockIdx.y;
    int p0b = blockIdx.x * 64;               // block's pooled px base
    int p0 = p0b + wv * 16;                  // wave's pooled px base

    __shared__ short lx[2][10][368];         // 14,720 B
    int pr0 = p0b / 56;
    int ohb = 2 * pr0;                       // first staged input row
    {
        const __hip_bfloat16* s0 = xp0 + (size_t)fr*XFRM + (size_t)ohb*XROW;
        const __hip_bfloat16* s1 = xp1 + (size_t)fr*XFRM + (size_t)ohb*XROW;
        for (int u = threadIdx.x; u < 900; u += 256) {
            int par = u / 450;
            int rem = u - par*450;
            int rr  = rem / 45;
            int c   = rem - rr*45;           // 16B unit within row
            const __hip_bfloat16* s = (par ? s1 : s0) + rr*XROW + c*8;
            *(uint4*)&lx[par][rr][c*8] = *(const uint4*)s;
        }
    }
    __syncthreads();

    const s8v* wbp = (const s8v*)cwb;
    s8v bfrag[6];
    #pragma unroll
    for (int ks = 0; ks < 6; ++ks) bfrag[ks] = wbp[ks*64 + lane];

    const unsigned* lx32 = (const unsigned*)&lx[0][0][0];

    f4v acc[4];
    #pragma unroll
    for (int j = 0; j < 4; ++j) {
        int mm = lane & 15;
        int pp = p0 + j*4 + (mm >> 2);
        int pos = mm & 3;
        int pr = pp / 56, pc = pp - pr*56;
        int lr = 2*pr - ohb + (pos >> 1);    // 0..3
        int ow = 2*pc + (pos & 1);
        const unsigned* xr = lx32 + ((ow & 1)*10 + lr)*184 + ((ow*3 + (ow & 1)) >> 1);

        f4v a4 = {0.f,0.f,0.f,0.f};
        #pragma unroll
        for (int ks = 0; ks < 6; ++ks) {
            int blk = ks*4 + quad;
            union { s8v v; unsigned u[4]; } av;
            av.v = (s8v){0,0,0,0,0,0,0,0};
            if (blk < 21) {
                int row = blk / 3;
                int off2 = (blk % 3) * 4;    // dwords
                const unsigned* p = xr + row*184 + off2;
                av.u[0] = p[0]; av.u[1] = p[1]; av.u[2] = p[2]; av.u[3] = p[3];
            }
            a4 = __builtin_amdgcn_mfma_f32_16x16x32_bf16(av.v, bfrag[ks], a4, 0,0,0);
        }
        acc[j] = a4;
    }

    int nlo = lane & 15;
    float bias_n = cb[nlo];
    #pragma unroll
    for (int j = 0; j < 4; ++j) {
        float* ap = (float*)&acc[j];
        float mx = fmaxf(fmaxf(ap[0], ap[1]), fmaxf(ap[2], ap[3]));
        float vv = fmaxf(mx + bias_n, 0.f);
        ((unsigned short*)pooled)[((size_t)fr*3136 + p0 + j*4 + quad)*16 + nlo] = f2bfu(vv);
    }
}

// Kernel 2 (R30): FUSED ConvLSTM step — zx-conv + h-conv + gates in ONE
// kernel; zx_mfma and the 47.8MB zx buffer are DELETED.
// Rationale: 8 structural rewrites (R19/R21/R22/R25/R23/R26/R28/R29) left
// per-step wall time invariant at ~12us regardless of in-kernel structure
// -> the window is fixed per-dependent-dispatch cost; in-kernel work rides
// inside it. So move zx_mfma's work INTO the step: both convs target the
// SAME accumulator layout (acc0..3 = i/f/g/o for 4 px, ch = lane&15), so
// we just keep accumulating: 5 MFMA with pooled-taps x wkb (VALID conv, no
// guards) + 5 MFMA with h-taps x wrb (SAME pad). Epilogue = R0's, minus
// the 4 zx loads (gates straight from accs; zx skips its bf16 round-trip,
// accuracy strictly improves). Wave structure = R0/R9 verified (16pt/wave,
// 365x4-wave blocks, guard wid<1458, no barriers).
__global__ __launch_bounds__(256, 2) void lstm_step_fused(
    const __hip_bfloat16* __restrict__ pooled,  // [128][56][56][16] bf16
    const __hip_bfloat16* __restrict__ h_in,    // [8,54,54,16] bf16
    __hip_bfloat16* __restrict__ h_out,
    float* __restrict__ cpl,                    // [16][23328] planar fp32
    const __hip_bfloat16* __restrict__ wkb,     // [4][5][64][8] bf16
    const __hip_bfloat16* __restrict__ wrb,     // [4][5][64][8] bf16
    const float* __restrict__ bias,             // [64]
    int t)
{
    int wid = (blockIdx.x << 2) + (threadIdx.x >> 6);
    if (wid >= 1458) return;                 // no barriers below
    int lane = threadIdx.x & 63;
    int quad = lane >> 4;
    int pt0  = wid << 4;
    int m    = pt0 + (lane & 15);

    int b  = m / SPIX;
    int r  = m % SPIX;
    int oh = r / WO, ow = r % WO;
    const __hip_bfloat16* pf = pooled + (size_t)(b*TT + t) * (HP*WP*16);
    const __hip_bfloat16* hb = h_in + (size_t)b * SPIX * 16;

    f4v acc0 = {0.f,0.f,0.f,0.f}, acc1 = acc0, acc2 = acc0, acc3 = acc0;
    const s8v* wkv = (const s8v*)wkb;
    const s8v* wrv = (const s8v*)wrb;

    // ---- zx part: VALID 3x3 conv over pooled (56x56), no guards ----
    #pragma unroll
    for (int ks = 0; ks < 5; ++ks) {
        int blk = ks*4 + quad;
        s8v a = (s8v){0,0,0,0,0,0,0,0};
        if (blk < 18) {
            int tap = blk >> 1, half = blk & 1;
            int ky = tap / 3, kx = tap - ky*3;
            a = *(const s8v*)(pf + ((size_t)(oh+ky)*WP + (ow+kx))*16 + half*8);
        }
        acc0 = __builtin_amdgcn_mfma_f32_16x16x32_bf16(a, wkv[(0*5+ks)*64 + lane], acc0, 0,0,0);
        acc1 = __builtin_amdgcn_mfma_f32_16x16x32_bf16(a, wkv[(1*5+ks)*64 + lane], acc1, 0,0,0);
        acc2 = __builtin_amdgcn_mfma_f32_16x16x32_bf16(a, wkv[(2*5+ks)*64 + lane], acc2, 0,0,0);
        acc3 = __builtin_amdgcn_mfma_f32_16x16x32_bf16(a, wkv[(3*5+ks)*64 + lane], acc3, 0,0,0);
    }

    // ---- h part: SAME-pad 3x3 conv over h_in (54x54), guarded ----
    #pragma unroll
    for (int ks = 0; ks < 5; ++ks) {
        int blk = ks*4 + quad;
        s8v a = (s8v){0,0,0,0,0,0,0,0};
        if (blk < 18) {
            int tap = blk >> 1, half = blk & 1;
            int ky = tap / 3, kx = tap - ky*3;
            int hy = oh + ky - 1, hx = ow + kx - 1;   // SAME pad
            if ((hy >= 0) & (hy < HO) & (hx >= 0) & (hx < WO))
                a = *(const s8v*)(hb + ((size_t)hy*WO + hx)*16 + half*8);
        }
        acc0 = __builtin_amdgcn_mfma_f32_16x16x32_bf16(a, wrv[(0*5+ks)*64 + lane], acc0, 0,0,0);
        acc1 = __builtin_amdgcn_mfma_f32_16x16x32_bf16(a, wrv[(1*5+ks)*64 + lane], acc1, 0,0,0);
        acc2 = __builtin_amdgcn_mfma_f32_16x16x32_bf16(a, wrv[(2*5+ks)*64 + lane], acc2, 0,0,0);
        acc3 = __builtin_amdgcn_mfma_f32_16x16x32_bf16(a, wrv[(3*5+ks)*64 + lane], acc3, 0,0,0);
    }

    // Epilogue: lane owns channel ch for pixels pm..pm+3 (one b: 2916%4==0).
    int ch = lane & 15;
    int pm = pt0 + quad*4;

    float4 cold = *(float4*)&cpl[(size_t)ch * NPIX + pm];
    float b_i = bias[ch], b_f = bias[16+ch], b_g = bias[32+ch], b_o = bias[48+ch];

    float4 cnew;
    unsigned short hn[4];
    float* co = &cold.x; float* cn = &cnew.x;
    float* a0 = (float*)&acc0; float* a1 = (float*)&acc1;
    float* a2 = (float*)&acc2; float* a3 = (float*)&acc3;
    #pragma unroll
    for (int reg = 0; reg < 4; ++reg) {
        float iv = hsig (a0[reg] + b_i);
        float fv = hsig (a1[reg] + b_f);
        float gv = tanhf(a2[reg] + b_g);
        float ov = hsig (a3[reg] + b_o);
        float cc = fv * co[reg] + iv * gv;
        cn[reg] = cc;
        hn[reg] = f2bfu(ov * tanhf(cc));
    }
    *(float4*)&cpl[(size_t)ch * NPIX + pm] = cnew;
    #pragma unroll
    for (int reg = 0; reg < 4; ++reg)
        ((unsigned short*)h_out)[(size_t)(pm + reg) * 16 + ch] = hn[reg];
}

// Kernel 3: spatial mean (bf16 h) -> dense(16->6) -> softmax. One block per b.
// R18: short8 loads, 1024 threads, parity-preserving LDS tree (verified win).
__global__ __launch_bounds__(1024) void head_kernel(
    const __hip_bfloat16* __restrict__ h,   // [8,54,54,16] bf16
    const float* __restrict__ dw,   // [16,6]
    const float* __restrict__ db,   // [6]
    float* __restrict__ out)        // [8,6]
{
    int b = blockIdx.x;
    int tid = threadIdx.x;
    const s8v* hb = (const s8v*)(h + (size_t)b * SPIX * 16);  // 5832 s8v per b

    float acc[8] = {0.f,0.f,0.f,0.f,0.f,0.f,0.f,0.f};
    for (int j = tid; j < SPIX*2; j += 1024) {
        s8v v = hb[j];
        #pragma unroll
        for (int k = 0; k < 8; ++k) acc[k] += bf2f((unsigned short)v[k]);
    }

    __shared__ float red[1024][8];           // 32 KB
    #pragma unroll
    for (int k = 0; k < 8; ++k) red[tid][k] = acc[k];
    __syncthreads();
    for (int st = 512; st >= 2; st >>= 1) {
        if (tid < st) {
            #pragma unroll
            for (int k = 0; k < 8; ++k) red[tid][k] += red[tid + st][k];
        }
        __syncthreads();
    }

    __shared__ float logits[8];
    if (tid < NC) {
        float l = db[tid];
        #pragma unroll
        for (int k = 0; k < 8; ++k) {
            l += (red[0][k] * (1.0f/2916.0f)) * dw[k*NC + tid];
            l += (red[1][k] * (1.0f/2916.0f)) * dw[(8+k)*NC + tid];
        }
        logits[tid] = l;
    }
    __syncthreads();
    if (tid < NC) {
        float m = -1e30f;
        for (int k = 0; k < NC; ++k) m = fmaxf(m, logits[k]);
        float e = expf(logits[tid] - m);
        float d = 0.0f;
        for (int k = 0; k < NC; ++k) d += expf(logits[k] - m);
        out[b*NC + tid] = e / d;
    }
}

extern "C" void kernel_launch(void* const* d_in, const int* in_sizes, int n_in,
                              void* d_out, int out_size, void* d_ws, size_t ws_size,
                              hipStream_t stream) {
    const float* x      = (const float*)d_in[0];
    const float* conv_w = (const float*)d_in[1];
    const float* conv_b = (const float*)d_in[2];
    const float* wk     = (const float*)d_in[3];
    const float* wr     = (const float*)d_in[4];
    const float* bias   = (const float*)d_in[5];
    const float* dw     = (const float*)d_in[6];
    const float* db     = (const float*)d_in[7];
    float* out = (float*)d_out;

    char* base = (char*)d_ws;
    __hip_bfloat16* pooled = (__hip_bfloat16*)base;                 // 12.85 MB
    __hip_bfloat16* hA  = pooled + POOLED_BF16;                     // 746 KB
    __hip_bfloat16* hB  = hA + NPIX*16;
    __hip_bfloat16* wkb = hB + NPIX*16;                             // 20 KB
    __hip_bfloat16* wrb = wkb + 10240;                              // 20 KB
    __hip_bfloat16* cwb = wrb + 10240;                              // 6 KB
    float* cpl = (float*)(cwb + 3072);                              // 1.49 MB
    // xpad parity copies live where zx used to (zx is deleted entirely).
    __hip_bfloat16* xp0 = (__hip_bfloat16*)(cpl + NPIX*16);         // 10.9 MB
    __hip_bfloat16* xp1 = xp0 + XPAD_ELEMS;                         // 10.9 MB

    // One prep dispatch: xpad + wk/wr/cw prepack + c0/h0 zero.
    prep_kernel<<<dim3(5950), dim3(256), 0, stream>>>(
        x, xp0, xp1, wk, wkb, wr, wrb, conv_w, cwb, cpl, hA);
    conv_mfma_kernel<<<dim3(49, 128), dim3(256), 0, stream>>>(xp0, xp1, cwb, conv_b, pooled);

    for (int t = 0; t < TT; ++t) {
        const __hip_bfloat16* hin  = (t & 1) ? hB : hA;
        __hip_bfloat16*       hout = (t & 1) ? hA : hB;
        lstm_step_fused<<<dim3(365), dim3(256), 0, stream>>>(
            pooled, hin, hout, cpl, wkb, wrb, bias, t);
    }
    // t=15 (odd) wrote hA
    head_kernel<<<dim3(8), dim3(1024), 0, stream>>>(hA, dw, db, out);
}